// Round 1
// baseline (1247.565 us; speedup 1.0000x reference)
//
#include <hip/hip_runtime.h>

// Problem constants: B=1, L=320, D=128, H=4, DH=32
#define LQ 320
#define NSEQ 320
#define NROWS (NSEQ*LQ)   // 102400
#define DDIM 128
#define NH 4
#define DHD 32
#define LN_EPS 1e-5f

// ---- bf16 helpers (OCP bf16 = top 16 bits of fp32, RNE pack) ----
__device__ inline float bf_lo(unsigned int u) { return __uint_as_float(u << 16); }
__device__ inline float bf_hi(unsigned int u) { return __uint_as_float(u & 0xffff0000u); }
__device__ inline unsigned short f2bf(float f) {
    unsigned int u = __float_as_uint(f);
    u += 0x7fffu + ((u >> 16) & 1u);
    return (unsigned short)(u >> 16);
}
__device__ inline unsigned int pack2(float a, float b) {
    return (unsigned int)f2bf(a) | ((unsigned int)f2bf(b) << 16);
}

// =====================================================================
// K1: LayerNorm + QKV projection.
// Block = 256 threads, 64 rows/block, grid 1600.
// zn staged in LDS as bf16 pairs [64][65] (pad=1 pair -> bank (r+dd)%32, conflict-free).
// w_qkv staged in 2 chunks of 192 cols, bf16 pairs [192][65].
// Micro-tile per thread: 4 rows x 12 cols (col = tx + 16*c -> 2-way LDS aliasing = free).
// Writes q/k/v to ws in [n][h][i][d] bf16 layout for K2.
// =====================================================================
__global__ __launch_bounds__(256) void k1_ln_qkv(
    const float* __restrict__ z, const float* __restrict__ ln_g, const float* __restrict__ ln_b,
    const float* __restrict__ w_qkv, const float* __restrict__ b_qkv,
    unsigned short* __restrict__ qws, unsigned short* __restrict__ kws,
    unsigned short* __restrict__ vws)
{
    __shared__ unsigned int znb[64 * 65];   // 16.6 KB
    __shared__ unsigned int wch[192 * 65];  // 49.9 KB
    const int tid = threadIdx.x;
    const int rowbase = blockIdx.x * 64;
    const int lane = tid & 63;
    const int wid = tid >> 6;

    // --- LayerNorm: each wave handles 16 rows; lane holds cols 2*lane, 2*lane+1 ---
    const float g0 = ln_g[2 * lane], g1 = ln_g[2 * lane + 1];
    const float bb0 = ln_b[2 * lane], bb1 = ln_b[2 * lane + 1];
    for (int r = wid; r < 64; r += 4) {
        const float2 v = *(const float2*)(z + (size_t)(rowbase + r) * DDIM + 2 * lane);
        float s = v.x + v.y;
        float s2 = v.x * v.x + v.y * v.y;
        #pragma unroll
        for (int off = 32; off > 0; off >>= 1) {
            s  += __shfl_xor(s, off, 64);
            s2 += __shfl_xor(s2, off, 64);
        }
        const float mu = s * (1.0f / 128.0f);
        const float var = s2 * (1.0f / 128.0f) - mu * mu;
        const float rs = rsqrtf(var + LN_EPS);
        const float zn0 = (v.x - mu) * rs * g0 + bb0;
        const float zn1 = (v.y - mu) * rs * g1 + bb1;
        znb[r * 65 + lane] = pack2(zn0, zn1);
    }

    const int tx = tid & 15, ty = tid >> 4;
    const float2* wp2 = (const float2*)w_qkv;

    for (int ch = 0; ch < 2; ++ch) {
        __syncthreads();  // LN visible (ch=0) / previous chunk's reads done (ch=1)
        for (int idx = tid; idx < 192 * 64; idx += 256) {
            const int c = idx >> 6, dd = idx & 63;
            const float2 wv = wp2[(size_t)(ch * 192 + c) * 64 + dd];
            wch[c * 65 + dd] = pack2(wv.x, wv.y);
        }
        __syncthreads();

        float acc[4][12];
        #pragma unroll
        for (int j = 0; j < 4; ++j)
            #pragma unroll
            for (int c = 0; c < 12; ++c) acc[j][c] = 0.f;

        #pragma unroll 4
        for (int dd = 0; dd < 64; ++dd) {
            float ax[4], ay[4];
            #pragma unroll
            for (int j = 0; j < 4; ++j) {
                const unsigned int u = znb[(4 * ty + j) * 65 + dd];
                ax[j] = bf_lo(u); ay[j] = bf_hi(u);
            }
            #pragma unroll
            for (int c = 0; c < 12; ++c) {
                const unsigned int u = wch[(tx + 16 * c) * 65 + dd];
                const float wx = bf_lo(u), wy = bf_hi(u);
                #pragma unroll
                for (int j = 0; j < 4; ++j) acc[j][c] += ax[j] * wx + ay[j] * wy;
            }
        }

        // epilogue: scatter to q/k/v [n][h][i][d] bf16
        #pragma unroll
        for (int j = 0; j < 4; ++j) {
            const int row = rowbase + 4 * ty + j;
            const int n = row / LQ;
            const int i = row - n * LQ;
            #pragma unroll
            for (int c = 0; c < 12; ++c) {
                const int cg = ch * 192 + tx + 16 * c;
                const int sect = cg >> 7;        // 0=q 1=k 2=v
                const int hd = cg & 127;
                const int hh = hd >> 5, d = hd & 31;
                unsigned short* dst = (sect == 0) ? qws : (sect == 1 ? kws : vws);
                dst[((size_t)((n * NH + hh) * LQ + i)) * DHD + d] = f2bf(acc[j][c] + b_qkv[cg]);
            }
        }
    }
}

// =====================================================================
// K2: attention per (n,h). Grid 1280, block 320 (one query per thread).
// K/V tiles staged in LDS as bf16 pairs (broadcast reads -> conflict-free).
// Two-pass softmax over the full 320-key row (no online rescale needed).
// =====================================================================
__global__ __launch_bounds__(320) void k2_attn(
    const unsigned short* __restrict__ qws, const unsigned short* __restrict__ kws,
    const unsigned short* __restrict__ vws, const int* __restrict__ mask,
    unsigned short* __restrict__ ows)
{
    __shared__ unsigned int ktU[LQ * 16];  // 20 KB
    __shared__ unsigned int vtU[LQ * 16];  // 20 KB
    __shared__ float bias[LQ];             // 1.25 KB
    const int tid = threadIdx.x;
    const int nh = blockIdx.x;
    const unsigned int* kp = (const unsigned int*)kws;
    const unsigned int* vp = (const unsigned int*)vws;
    const unsigned int* qp = (const unsigned int*)qws;
    const int basep = nh * (LQ * 16);

    for (int idx = tid; idx < LQ * 16; idx += 320) {
        ktU[idx] = kp[basep + idx];
        vtU[idx] = vp[basep + idx];
    }
    if (tid < LQ) bias[tid] = (mask[tid] > 0) ? 0.f : -1e30f;
    __syncthreads();

    const int qi = tid;
    float qf[32];
    #pragma unroll
    for (int dd = 0; dd < 16; ++dd) {
        const unsigned int u = qp[basep + qi * 16 + dd];
        qf[2 * dd] = bf_lo(u); qf[2 * dd + 1] = bf_hi(u);
    }
    const float scale = 0.17677669529663687f;  // 1/sqrt(32)

    // pass 1: row max
    float m = -1e30f;
    for (int k = 0; k < LQ; ++k) {
        float s = 0.f;
        #pragma unroll
        for (int dd = 0; dd < 16; ++dd) {
            const unsigned int u = ktU[k * 16 + dd];
            s += qf[2 * dd] * bf_lo(u) + qf[2 * dd + 1] * bf_hi(u);
        }
        m = fmaxf(m, s * scale + bias[k]);
    }

    // pass 2: exp-sum + PV
    float l = 0.f;
    float acc[32];
    #pragma unroll
    for (int d = 0; d < 32; ++d) acc[d] = 0.f;
    for (int k = 0; k < LQ; ++k) {
        float s = 0.f;
        #pragma unroll
        for (int dd = 0; dd < 16; ++dd) {
            const unsigned int u = ktU[k * 16 + dd];
            s += qf[2 * dd] * bf_lo(u) + qf[2 * dd + 1] * bf_hi(u);
        }
        const float e = __expf(s * scale + bias[k] - m);
        l += e;
        #pragma unroll
        for (int dd = 0; dd < 16; ++dd) {
            const unsigned int u = vtU[k * 16 + dd];
            acc[2 * dd]     += e * bf_lo(u);
            acc[2 * dd + 1] += e * bf_hi(u);
        }
    }
    const float inv = 1.0f / l;
    const int n = nh >> 2, h = nh & 3;
    unsigned short* orow = ows + (size_t)(n * LQ + qi) * DDIM + h * DHD;
    #pragma unroll
    for (int d = 0; d < 32; ++d) orow[d] = f2bf(acc[d] * inv);
}

// =====================================================================
// K3: out projection + residual. Block 256, 64 rows/block, grid 1600.
// w_out (bf16 pairs [128][65]) + o tile ([64][65]) in LDS.
// Thread tile 4 rows x 8 cols, col = tx + 16*c (2-way aliasing = free;
// epilogue stores coalesced across tx).
// =====================================================================
__global__ __launch_bounds__(256) void k3_out(
    const unsigned short* __restrict__ ows, const float* __restrict__ w_out,
    const float* __restrict__ b_out, const float* __restrict__ z,
    float* __restrict__ out)
{
    __shared__ unsigned int wt[128 * 65];  // 33.3 KB
    __shared__ unsigned int ot[64 * 65];   // 16.6 KB
    const int tid = threadIdx.x;
    const int rowbase = blockIdx.x * 64;

    const float2* wp2 = (const float2*)w_out;
    for (int idx = tid; idx < 128 * 64; idx += 256) {
        const int c = idx >> 6, dd = idx & 63;
        const float2 wv = wp2[idx];
        wt[c * 65 + dd] = pack2(wv.x, wv.y);
    }
    const unsigned int* op = (const unsigned int*)ows;
    for (int idx = tid; idx < 64 * 64; idx += 256) {
        const int r = idx >> 6, dd = idx & 63;
        ot[r * 65 + dd] = op[(size_t)(rowbase + r) * 64 + dd];
    }
    __syncthreads();

    const int tx = tid & 15, ty = tid >> 4;
    float acc[4][8];
    #pragma unroll
    for (int j = 0; j < 4; ++j)
        #pragma unroll
        for (int c = 0; c < 8; ++c) acc[j][c] = 0.f;

    #pragma unroll 4
    for (int dd = 0; dd < 64; ++dd) {
        float ax[4], ay[4];
        #pragma unroll
        for (int j = 0; j < 4; ++j) {
            const unsigned int u = ot[(4 * ty + j) * 65 + dd];
            ax[j] = bf_lo(u); ay[j] = bf_hi(u);
        }
        #pragma unroll
        for (int c = 0; c < 8; ++c) {
            const unsigned int u = wt[(tx + 16 * c) * 65 + dd];
            const float wx = bf_lo(u), wy = bf_hi(u);
            #pragma unroll
            for (int j = 0; j < 4; ++j) acc[j][c] += ax[j] * wx + ay[j] * wy;
        }
    }

    #pragma unroll
    for (int j = 0; j < 4; ++j) {
        const int row = rowbase + 4 * ty + j;
        const float* zr = z + (size_t)row * DDIM;
        float* outr = out + (size_t)row * DDIM;
        #pragma unroll
        for (int c = 0; c < 8; ++c) {
            const int cg = tx + 16 * c;
            outr[cg] = acc[j][c] + b_out[cg] + zr[cg];
        }
    }
}

extern "C" void kernel_launch(void* const* d_in, const int* in_sizes, int n_in,
                              void* d_out, int out_size, void* d_ws, size_t ws_size,
                              hipStream_t stream) {
    const float* z     = (const float*)d_in[0];
    const int*   mask  = (const int*)d_in[1];
    const float* ln_g  = (const float*)d_in[2];
    const float* ln_b  = (const float*)d_in[3];
    const float* w_qkv = (const float*)d_in[4];
    const float* b_qkv = (const float*)d_in[5];
    const float* w_out = (const float*)d_in[6];
    const float* b_out = (const float*)d_in[7];
    float* out = (float*)d_out;

    // ws layout (bf16): q, k, v each [NSEQ][H][L][DH], then o [NROWS][D]
    unsigned short* ws = (unsigned short*)d_ws;
    const size_t qE = (size_t)NSEQ * NH * LQ * DHD;  // 13,107,200
    unsigned short* qws = ws;
    unsigned short* kws = qws + qE;
    unsigned short* vws = kws + qE;
    unsigned short* ows = vws + qE;  // NROWS * DDIM

    hipLaunchKernelGGL(k1_ln_qkv, dim3(NROWS / 64), dim3(256), 0, stream,
                       z, ln_g, ln_b, w_qkv, b_qkv, qws, kws, vws);
    hipLaunchKernelGGL(k2_attn, dim3(NSEQ * NH), dim3(320), 0, stream,
                       qws, kws, vws, mask, ows);
    hipLaunchKernelGGL(k3_out, dim3(NROWS / 64), dim3(256), 0, stream,
                       ows, w_out, b_out, z, out);
}

// Round 2
// 559.197 us; speedup vs baseline: 2.2310x; 2.2310x over previous
//
#include <hip/hip_runtime.h>

// Problem constants: B=1, L=320, D=128, H=4, DH=32
#define LQ 320
#define NSEQ 320
#define NROWS (NSEQ*LQ)   // 102400
#define DDIM 128
#define NH 4
#define DHD 32
#define LN_EPS 1e-5f
#define QSCALE 0.17677669529663687f  // 1/sqrt(32), folded into q at K1

typedef __bf16 bf16x8 __attribute__((ext_vector_type(8)));
typedef float f32x4 __attribute__((ext_vector_type(4)));
union FragU { unsigned int u[4]; bf16x8 v; };

// ---- bf16 helpers (OCP bf16 = top 16 bits of fp32, RNE pack) ----
__device__ inline float bf_lo(unsigned int u) { return __uint_as_float(u << 16); }
__device__ inline float bf_hi(unsigned int u) { return __uint_as_float(u & 0xffff0000u); }
__device__ inline unsigned short f2bf(float f) {
    unsigned int u = __float_as_uint(f);
    u += 0x7fffu + ((u >> 16) & 1u);
    return (unsigned short)(u >> 16);
}
__device__ inline unsigned int pack2(float a, float b) {
    return (unsigned int)f2bf(a) | ((unsigned int)f2bf(b) << 16);
}

// =====================================================================
// K1: LayerNorm + QKV projection (as round 1) with two epilogue changes:
//  - q prescaled by 1/sqrt(DH)
//  - v stored TRANSPOSED per head: [n][h][d][i]  (for K2's PV B-frags)
// =====================================================================
__global__ __launch_bounds__(256) void k1_ln_qkv(
    const float* __restrict__ z, const float* __restrict__ ln_g, const float* __restrict__ ln_b,
    const float* __restrict__ w_qkv, const float* __restrict__ b_qkv,
    unsigned short* __restrict__ qws, unsigned short* __restrict__ kws,
    unsigned short* __restrict__ vws)
{
    __shared__ unsigned int znb[64 * 65];   // 16.6 KB
    __shared__ unsigned int wch[192 * 65];  // 49.9 KB
    const int tid = threadIdx.x;
    const int rowbase = blockIdx.x * 64;
    const int lane = tid & 63;
    const int wid = tid >> 6;

    const float g0 = ln_g[2 * lane], g1 = ln_g[2 * lane + 1];
    const float bb0 = ln_b[2 * lane], bb1 = ln_b[2 * lane + 1];
    for (int r = wid; r < 64; r += 4) {
        const float2 v = *(const float2*)(z + (size_t)(rowbase + r) * DDIM + 2 * lane);
        float s = v.x + v.y;
        float s2 = v.x * v.x + v.y * v.y;
        #pragma unroll
        for (int off = 32; off > 0; off >>= 1) {
            s  += __shfl_xor(s, off, 64);
            s2 += __shfl_xor(s2, off, 64);
        }
        const float mu = s * (1.0f / 128.0f);
        const float var = s2 * (1.0f / 128.0f) - mu * mu;
        const float rs = rsqrtf(var + LN_EPS);
        const float zn0 = (v.x - mu) * rs * g0 + bb0;
        const float zn1 = (v.y - mu) * rs * g1 + bb1;
        znb[r * 65 + lane] = pack2(zn0, zn1);
    }

    const int tx = tid & 15, ty = tid >> 4;
    const float2* wp2 = (const float2*)w_qkv;

    for (int ch = 0; ch < 2; ++ch) {
        __syncthreads();
        for (int idx = tid; idx < 192 * 64; idx += 256) {
            const int c = idx >> 6, dd = idx & 63;
            const float2 wv = wp2[(size_t)(ch * 192 + c) * 64 + dd];
            wch[c * 65 + dd] = pack2(wv.x, wv.y);
        }
        __syncthreads();

        float acc[4][12];
        #pragma unroll
        for (int j = 0; j < 4; ++j)
            #pragma unroll
            for (int c = 0; c < 12; ++c) acc[j][c] = 0.f;

        #pragma unroll 4
        for (int dd = 0; dd < 64; ++dd) {
            float ax[4], ay[4];
            #pragma unroll
            for (int j = 0; j < 4; ++j) {
                const unsigned int u = znb[(4 * ty + j) * 65 + dd];
                ax[j] = bf_lo(u); ay[j] = bf_hi(u);
            }
            #pragma unroll
            for (int c = 0; c < 12; ++c) {
                const unsigned int u = wch[(tx + 16 * c) * 65 + dd];
                const float wx = bf_lo(u), wy = bf_hi(u);
                #pragma unroll
                for (int j = 0; j < 4; ++j) acc[j][c] += ax[j] * wx + ay[j] * wy;
            }
        }

        #pragma unroll
        for (int j = 0; j < 4; ++j) {
            const int row = rowbase + 4 * ty + j;
            const int n = row / LQ;
            const int i = row - n * LQ;
            #pragma unroll
            for (int c = 0; c < 12; ++c) {
                const int cg = ch * 192 + tx + 16 * c;
                const int sect = cg >> 7;        // 0=q 1=k 2=v
                const int hd = cg & 127;
                const int hh = hd >> 5, d = hd & 31;
                const float val = acc[j][c] + b_qkv[cg];
                if (sect == 0) {
                    qws[((size_t)((n * NH + hh) * LQ + i)) * DHD + d] = f2bf(val * QSCALE);
                } else if (sect == 1) {
                    kws[((size_t)((n * NH + hh) * LQ + i)) * DHD + d] = f2bf(val);
                } else {
                    // transposed: [n][h][d][i]
                    vws[((size_t)((n * NH + hh) * DHD + d)) * LQ + i] = f2bf(val);
                }
            }
        }
    }
}

// =====================================================================
// K2: MFMA attention. Grid 1280 (one block per n,h), 256 threads (4 waves).
// Each wave owns 5 Q-tiles of 16 queries (qt = wid*5 + it).
// Per Q-tile:
//   S^T tiles (20): mfma(A=K-tile, B=Q) -> C: col=q(lane&15), row=key(4g+reg)
//   softmax per q: per-lane reduce over 80 keys + shfl_xor(16,32)
//   P (normalized, bf16-pair packed) -> A-operand layout via 8 ds_bpermute
//   + 4 selects per 32-key chunk (no LDS round trip: q=lane&15 already matches)
//   O tiles (2 x 16d): mfma(A=P, B=V^T from LDS)
// LDS: K [320][20 uints] 25.6KB (2-way bank aliasing = free) +
//      VT [32][164 uints] 21KB (16B aligned rows) + bias = 48KB.
// =====================================================================
#define KSTR 20
#define VSTR 164
__global__ __launch_bounds__(256) void k2_attn_mfma(
    const unsigned short* __restrict__ qws, const unsigned short* __restrict__ kws,
    const unsigned short* __restrict__ vtws, const int* __restrict__ mask,
    unsigned short* __restrict__ ows)
{
    __shared__ unsigned int kT[LQ * KSTR];   // 25.6 KB
    __shared__ unsigned int vT[DHD * VSTR];  // 21.0 KB
    __shared__ float bias[LQ];               // 1.25 KB
    const int tid = threadIdx.x;
    const int nh = blockIdx.x;
    const int lane = tid & 63;
    const int wid = tid >> 6;
    const int qn = lane & 15;       // query col / key row / dim col within tile
    const int gd = lane >> 4;       // lane group 0..3

    // ---- stage K: global [nh][320][32]bf16 = [nh][320][16]uints ----
    const unsigned int* kp = (const unsigned int*)kws + (size_t)nh * LQ * 16;
    for (int idx = tid; idx < LQ * 16; idx += 256) {
        const int r = idx >> 4, c = idx & 15;
        kT[r * KSTR + c] = kp[idx];
    }
    // ---- stage VT: global [nh][32][320]bf16 = [nh][32][160]uints ----
    const unsigned int* vp = (const unsigned int*)vtws + (size_t)nh * DHD * 160;
    for (int idx = tid; idx < DHD * 160; idx += 256) {
        const int r = idx / 160, c = idx - r * 160;
        vT[r * VSTR + c] = vp[idx];
    }
    for (int i = tid; i < LQ; i += 256) bias[i] = (mask[i] > 0) ? 0.f : -1e30f;
    __syncthreads();

    const f32x4 zero4 = {0.f, 0.f, 0.f, 0.f};
    const int alo = (((gd & 1) << 5) | qn) << 2;  // bperm addr: src lane group 2*(gd&1)
    const int ahi = alo + 64;                     // src lane group 2*(gd&1)+1
    const bool hiT = (gd >= 2);                   // which 16-key C-tile feeds this lane group

    const int n = nh >> 2, h = nh & 3;

    for (int it = 0; it < 5; ++it) {
        const int qt = wid * 5 + it;

        // Q B-frag from global: lane q=qn, dims 8*gd..+7 (prescaled by 1/sqrt(DH))
        FragU qf;
        qf.v = *(const bf16x8*)(qws + ((size_t)nh * LQ + qt * 16 + qn) * DHD + 8 * gd);

        // ---- QK^T: 20 S^T tiles ----
        f32x4 st[20];
        #pragma unroll
        for (int kt = 0; kt < 20; ++kt) {
            const unsigned int* kptr = &kT[(kt * 16 + qn) * KSTR + 4 * gd];
            FragU kf;
            const uint2 ka = *(const uint2*)kptr;
            const uint2 kb = *(const uint2*)(kptr + 2);
            kf.u[0] = ka.x; kf.u[1] = ka.y; kf.u[2] = kb.x; kf.u[3] = kb.y;
            st[kt] = __builtin_amdgcn_mfma_f32_16x16x32_bf16(kf.v, qf.v, zero4, 0, 0, 0);
        }

        // ---- bias + softmax (per q = per lane col, keys across regs/groups/tiles) ----
        float m = -1e30f;
        #pragma unroll
        for (int kt = 0; kt < 20; ++kt) {
            const float4 bv = *(const float4*)(bias + kt * 16 + 4 * gd);
            st[kt][0] += bv.x; st[kt][1] += bv.y; st[kt][2] += bv.z; st[kt][3] += bv.w;
            m = fmaxf(m, fmaxf(fmaxf(st[kt][0], st[kt][1]), fmaxf(st[kt][2], st[kt][3])));
        }
        m = fmaxf(m, __shfl_xor(m, 16, 64));
        m = fmaxf(m, __shfl_xor(m, 32, 64));

        float l = 0.f;
        #pragma unroll
        for (int kt = 0; kt < 20; ++kt) {
            st[kt][0] = __expf(st[kt][0] - m);
            st[kt][1] = __expf(st[kt][1] - m);
            st[kt][2] = __expf(st[kt][2] - m);
            st[kt][3] = __expf(st[kt][3] - m);
            l += st[kt][0] + st[kt][1] + st[kt][2] + st[kt][3];
        }
        l += __shfl_xor(l, 16, 64);
        l += __shfl_xor(l, 32, 64);
        const float inv = 1.0f / l;

        // normalized P packed to bf16 pairs (regs r0|r1, r2|r3 per tile)
        unsigned int u01[20], u23[20];
        #pragma unroll
        for (int kt = 0; kt < 20; ++kt) {
            u01[kt] = pack2(st[kt][0] * inv, st[kt][1] * inv);
            u23[kt] = pack2(st[kt][2] * inv, st[kt][3] * inv);
        }

        // ---- PV: O[16q][32d] = P(16x320) * V(320x32), per 32-key chunk ----
        f32x4 o0 = zero4, o1 = zero4;
        #pragma unroll
        for (int kc = 0; kc < 10; ++kc) {
            const int t0 = 2 * kc, t1 = 2 * kc + 1;
            // A-frag of P via cross-lane-group permutes
            FragU pa;
            {
                const int a0 = __builtin_amdgcn_ds_bpermute(alo, (int)u01[t0]);
                const int b0 = __builtin_amdgcn_ds_bpermute(alo, (int)u01[t1]);
                const int a1 = __builtin_amdgcn_ds_bpermute(alo, (int)u23[t0]);
                const int b1 = __builtin_amdgcn_ds_bpermute(alo, (int)u23[t1]);
                const int a2 = __builtin_amdgcn_ds_bpermute(ahi, (int)u01[t0]);
                const int b2 = __builtin_amdgcn_ds_bpermute(ahi, (int)u01[t1]);
                const int a3 = __builtin_amdgcn_ds_bpermute(ahi, (int)u23[t0]);
                const int b3 = __builtin_amdgcn_ds_bpermute(ahi, (int)u23[t1]);
                pa.u[0] = (unsigned int)(hiT ? b0 : a0);
                pa.u[1] = (unsigned int)(hiT ? b1 : a1);
                pa.u[2] = (unsigned int)(hiT ? b2 : a2);
                pa.u[3] = (unsigned int)(hiT ? b3 : a3);
            }
            // B-frags of V^T: lane d = dt*16+qn, keys 32kc+8g..+7
            FragU bv0, bv1;
            {
                const uint4 x = *(const uint4*)&vT[(0 * 16 + qn) * VSTR + 16 * kc + 4 * gd];
                bv0.u[0] = x.x; bv0.u[1] = x.y; bv0.u[2] = x.z; bv0.u[3] = x.w;
                const uint4 y = *(const uint4*)&vT[(1 * 16 + qn) * VSTR + 16 * kc + 4 * gd];
                bv1.u[0] = y.x; bv1.u[1] = y.y; bv1.u[2] = y.z; bv1.u[3] = y.w;
            }
            o0 = __builtin_amdgcn_mfma_f32_16x16x32_bf16(pa.v, bv0.v, o0, 0, 0, 0);
            o1 = __builtin_amdgcn_mfma_f32_16x16x32_bf16(pa.v, bv1.v, o1, 0, 0, 0);
        }

        // ---- epilogue: O C-layout col=d(lane&15), row=q(4g+r) ----
        #pragma unroll
        for (int r = 0; r < 4; ++r) {
            const int qg = qt * 16 + 4 * gd + r;
            unsigned short* orow = ows + ((size_t)(n * LQ + qg)) * DDIM + h * DHD + qn;
            orow[0]  = f2bf(o0[r]);
            orow[16] = f2bf(o1[r]);
        }
    }
}

// =====================================================================
// K3: out projection + residual (unchanged from round 1).
// =====================================================================
__global__ __launch_bounds__(256) void k3_out(
    const unsigned short* __restrict__ ows, const float* __restrict__ w_out,
    const float* __restrict__ b_out, const float* __restrict__ z,
    float* __restrict__ out)
{
    __shared__ unsigned int wt[128 * 65];  // 33.3 KB
    __shared__ unsigned int ot[64 * 65];   // 16.6 KB
    const int tid = threadIdx.x;
    const int rowbase = blockIdx.x * 64;

    const float2* wp2 = (const float2*)w_out;
    for (int idx = tid; idx < 128 * 64; idx += 256) {
        const int c = idx >> 6, dd = idx & 63;
        const float2 wv = wp2[idx];
        wt[c * 65 + dd] = pack2(wv.x, wv.y);
    }
    const unsigned int* op = (const unsigned int*)ows;
    for (int idx = tid; idx < 64 * 64; idx += 256) {
        const int r = idx >> 6, dd = idx & 63;
        ot[r * 65 + dd] = op[(size_t)(rowbase + r) * 64 + dd];
    }
    __syncthreads();

    const int tx = tid & 15, ty = tid >> 4;
    float acc[4][8];
    #pragma unroll
    for (int j = 0; j < 4; ++j)
        #pragma unroll
        for (int c = 0; c < 8; ++c) acc[j][c] = 0.f;

    #pragma unroll 4
    for (int dd = 0; dd < 64; ++dd) {
        float ax[4], ay[4];
        #pragma unroll
        for (int j = 0; j < 4; ++j) {
            const unsigned int u = ot[(4 * ty + j) * 65 + dd];
            ax[j] = bf_lo(u); ay[j] = bf_hi(u);
        }
        #pragma unroll
        for (int c = 0; c < 8; ++c) {
            const unsigned int u = wt[(tx + 16 * c) * 65 + dd];
            const float wx = bf_lo(u), wy = bf_hi(u);
            #pragma unroll
            for (int j = 0; j < 4; ++j) acc[j][c] += ax[j] * wx + ay[j] * wy;
        }
    }

    #pragma unroll
    for (int j = 0; j < 4; ++j) {
        const int row = rowbase + 4 * ty + j;
        const float* zr = z + (size_t)row * DDIM;
        float* outr = out + (size_t)row * DDIM;
        #pragma unroll
        for (int c = 0; c < 8; ++c) {
            const int cg = tx + 16 * c;
            outr[cg] = acc[j][c] + b_out[cg] + zr[cg];
        }
    }
}

extern "C" void kernel_launch(void* const* d_in, const int* in_sizes, int n_in,
                              void* d_out, int out_size, void* d_ws, size_t ws_size,
                              hipStream_t stream) {
    const float* z     = (const float*)d_in[0];
    const int*   mask  = (const int*)d_in[1];
    const float* ln_g  = (const float*)d_in[2];
    const float* ln_b  = (const float*)d_in[3];
    const float* w_qkv = (const float*)d_in[4];
    const float* b_qkv = (const float*)d_in[5];
    const float* w_out = (const float*)d_in[6];
    const float* b_out = (const float*)d_in[7];
    float* out = (float*)d_out;

    // ws layout (bf16): q [n][h][i][d], k [n][h][i][d], v TRANSPOSED [n][h][d][i], o [row][D]
    unsigned short* ws = (unsigned short*)d_ws;
    const size_t qE = (size_t)NSEQ * NH * LQ * DHD;  // 13,107,200
    unsigned short* qws = ws;
    unsigned short* kws = qws + qE;
    unsigned short* vws = kws + qE;
    unsigned short* ows = vws + qE;  // NROWS * DDIM

    hipLaunchKernelGGL(k1_ln_qkv, dim3(NROWS / 64), dim3(256), 0, stream,
                       z, ln_g, ln_b, w_qkv, b_qkv, qws, kws, vws);
    hipLaunchKernelGGL(k2_attn_mfma, dim3(NSEQ * NH), dim3(256), 0, stream,
                       qws, kws, vws, mask, ows);
    hipLaunchKernelGGL(k3_out, dim3(NROWS / 64), dim3(256), 0, stream,
                       ows, w_out, b_out, z, out);
}

// Round 3
// 465.875 us; speedup vs baseline: 2.6779x; 1.2003x over previous
//
#include <hip/hip_runtime.h>

// Problem constants: B=1, L=320, D=128, H=4, DH=32
#define LQ 320
#define NSEQ 320
#define NROWS (NSEQ*LQ)   // 102400
#define DDIM 128
#define NH 4
#define DHD 32
#define LN_EPS 1e-5f
#define QSCALE 0.17677669529663687f  // 1/sqrt(32), folded into q at K1

typedef __bf16 bf16x8 __attribute__((ext_vector_type(8)));
typedef float f32x4 __attribute__((ext_vector_type(4)));
union FragU { unsigned int u[4]; bf16x8 v; };

// ---- bf16 helpers (OCP bf16 = top 16 bits of fp32, RNE pack) ----
__device__ inline float bf_lo(unsigned int u) { return __uint_as_float(u << 16); }
__device__ inline float bf_hi(unsigned int u) { return __uint_as_float(u & 0xffff0000u); }
__device__ inline unsigned short f2bf(float f) {
    unsigned int u = __float_as_uint(f);
    u += 0x7fffu + ((u >> 16) & 1u);
    return (unsigned short)(u >> 16);
}
__device__ inline unsigned int pack2(float a, float b) {
    return (unsigned int)f2bf(a) | ((unsigned int)f2bf(b) << 16);
}

// =====================================================================
// K1: LayerNorm + QKV projection, MFMA version.
// Block 256 (4 waves), 64 rows/block, grid 1600.
// LDS: full W bf16 [384 rows][68 uints] (A/B-frag-ready, 2-way bank
//      aliasing = free) 104.4 KB + zn [64][68] 17.4 KB = 121.9 KB.
// Wave tile: M=64 (4 rowgroups of 16) x N=96 (6 n-tiles of 16), K=128
// (4 k-steps of 32). 96 mfma / 40 ds_read_b128 per wave.
// Epilogue: q prescaled by 1/sqrt(DH); v stored transposed [n][h][d][i].
// =====================================================================
__global__ __launch_bounds__(256) void k1_ln_qkv(
    const float* __restrict__ z, const float* __restrict__ ln_g, const float* __restrict__ ln_b,
    const float* __restrict__ w_qkv, const float* __restrict__ b_qkv,
    unsigned short* __restrict__ qws, unsigned short* __restrict__ kws,
    unsigned short* __restrict__ vws)
{
    __shared__ unsigned int wlds[384 * 68];  // 104448 B
    __shared__ unsigned int znb[64 * 68];    // 17408 B
    const int tid = threadIdx.x;
    const int rowbase = blockIdx.x * 64;
    const int lane = tid & 63;
    const int wid = tid >> 6;

    // --- LayerNorm: wave handles 16 rows; lane holds cols 2*lane, 2*lane+1 ---
    const float g0 = ln_g[2 * lane], g1 = ln_g[2 * lane + 1];
    const float bb0 = ln_b[2 * lane], bb1 = ln_b[2 * lane + 1];
    #pragma unroll 1
    for (int r = wid; r < 64; r += 4) {
        const float2 v = *(const float2*)(z + (size_t)(rowbase + r) * DDIM + 2 * lane);
        float s = v.x + v.y;
        float s2 = v.x * v.x + v.y * v.y;
        #pragma unroll
        for (int off = 32; off > 0; off >>= 1) {
            s  += __shfl_xor(s, off, 64);
            s2 += __shfl_xor(s2, off, 64);
        }
        const float mu = s * (1.0f / 128.0f);
        const float var = s2 * (1.0f / 128.0f) - mu * mu;
        const float rs = rsqrtf(var + LN_EPS);
        znb[r * 68 + lane] = pack2((v.x - mu) * rs * g0 + bb0, (v.y - mu) * rs * g1 + bb1);
    }

    // --- stage full w_qkv fp32 -> bf16 LDS [384][68] ---
    const float4* wp4 = (const float4*)w_qkv;
    #pragma unroll 1
    for (int idx = tid; idx < 384 * 32; idx += 256) {
        const int row = idx >> 5, c4 = idx & 31;
        const float4 w4 = wp4[idx];
        wlds[row * 68 + 2 * c4]     = pack2(w4.x, w4.y);
        wlds[row * 68 + 2 * c4 + 1] = pack2(w4.z, w4.w);
    }
    __syncthreads();

    const int qn = lane & 15, gd = lane >> 4;
    const f32x4 zero4 = {0.f, 0.f, 0.f, 0.f};
    f32x4 acc[4][6];
    #pragma unroll
    for (int rg = 0; rg < 4; ++rg)
        #pragma unroll
        for (int nt = 0; nt < 6; ++nt) acc[rg][nt] = zero4;

    #pragma unroll
    for (int kt = 0; kt < 4; ++kt) {
        FragU af[4];
        #pragma unroll
        for (int rg = 0; rg < 4; ++rg)
            af[rg].v = *(const bf16x8*)&znb[(16 * rg + qn) * 68 + 16 * kt + 4 * gd];
        #pragma unroll
        for (int nt = 0; nt < 6; ++nt) {
            FragU bf;
            bf.v = *(const bf16x8*)&wlds[(wid * 96 + nt * 16 + qn) * 68 + 16 * kt + 4 * gd];
            #pragma unroll
            for (int rg = 0; rg < 4; ++rg)
                acc[rg][nt] = __builtin_amdgcn_mfma_f32_16x16x32_bf16(af[rg].v, bf.v, acc[rg][nt], 0, 0, 0);
        }
    }

    // --- epilogue: C col = n (lane&15 within tile), row m = 16*rg + 4*gd + r ---
    const int n = rowbase / LQ;          // 64 | 320 -> single n per block
    const int ibase = rowbase - n * LQ;
    float bq[6];
    #pragma unroll
    for (int nt = 0; nt < 6; ++nt) bq[nt] = b_qkv[wid * 96 + nt * 16 + qn];

    #pragma unroll
    for (int rg = 0; rg < 4; ++rg) {
        #pragma unroll
        for (int r = 0; r < 4; ++r) {
            const int i = ibase + 16 * rg + 4 * gd + r;
            #pragma unroll
            for (int nt = 0; nt < 6; ++nt) {
                const int cg = wid * 96 + nt * 16 + qn;
                const float val = acc[rg][nt][r] + bq[nt];
                const int sect = cg >> 7;        // wave-uniform per nt
                const int hd = cg & 127;
                const int hh = hd >> 5, d = hd & 31;
                if (sect == 0) {
                    qws[((size_t)((n * NH + hh) * LQ + i)) * DHD + d] = f2bf(val * QSCALE);
                } else if (sect == 1) {
                    kws[((size_t)((n * NH + hh) * LQ + i)) * DHD + d] = f2bf(val);
                } else {
                    vws[((size_t)((n * NH + hh) * DHD + d)) * LQ + i] = f2bf(val);
                }
            }
        }
    }
}

// =====================================================================
// K2: MFMA attention. Grid 1280 (one block per n,h), 256 threads (4 waves).
// Round-3 changes: `#pragma unroll 1` on the Q-tile loop (prevent 5x
// register-set unroll -> scratch spills) and inline P packing in the PV
// loop (no u01/u23[20] arrays).
// =====================================================================
#define KSTR 20
#define VSTR 164
__global__ __launch_bounds__(256) void k2_attn_mfma(
    const unsigned short* __restrict__ qws, const unsigned short* __restrict__ kws,
    const unsigned short* __restrict__ vtws, const int* __restrict__ mask,
    unsigned short* __restrict__ ows)
{
    __shared__ unsigned int kT[LQ * KSTR];   // 25.6 KB
    __shared__ unsigned int vT[DHD * VSTR];  // 21.0 KB
    __shared__ float bias[LQ];               // 1.25 KB
    const int tid = threadIdx.x;
    const int nh = blockIdx.x;
    const int lane = tid & 63;
    const int wid = tid >> 6;
    const int qn = lane & 15;
    const int gd = lane >> 4;

    const unsigned int* kp = (const unsigned int*)kws + (size_t)nh * LQ * 16;
    #pragma unroll 1
    for (int idx = tid; idx < LQ * 16; idx += 256) {
        const int r = idx >> 4, c = idx & 15;
        kT[r * KSTR + c] = kp[idx];
    }
    const unsigned int* vp = (const unsigned int*)vtws + (size_t)nh * DHD * 160;
    #pragma unroll 1
    for (int idx = tid; idx < DHD * 160; idx += 256) {
        const int r = idx / 160, c = idx - r * 160;
        vT[r * VSTR + c] = vp[idx];
    }
    for (int i = tid; i < LQ; i += 256) bias[i] = (mask[i] > 0) ? 0.f : -1e30f;
    __syncthreads();

    const f32x4 zero4 = {0.f, 0.f, 0.f, 0.f};
    const int alo = (((gd & 1) << 5) | qn) << 2;
    const int ahi = alo + 64;
    const bool hiT = (gd >= 2);
    const int n = nh >> 2, h = nh & 3;

    #pragma unroll 1
    for (int it = 0; it < 5; ++it) {
        const int qt = wid * 5 + it;

        FragU qf;
        qf.v = *(const bf16x8*)(qws + ((size_t)nh * LQ + qt * 16 + qn) * DHD + 8 * gd);

        // ---- QK^T: 20 S^T tiles ----
        f32x4 st[20];
        #pragma unroll
        for (int kt = 0; kt < 20; ++kt) {
            const unsigned int* kptr = &kT[(kt * 16 + qn) * KSTR + 4 * gd];
            FragU kf;
            const uint2 ka = *(const uint2*)kptr;
            const uint2 kb = *(const uint2*)(kptr + 2);
            kf.u[0] = ka.x; kf.u[1] = ka.y; kf.u[2] = kb.x; kf.u[3] = kb.y;
            st[kt] = __builtin_amdgcn_mfma_f32_16x16x32_bf16(kf.v, qf.v, zero4, 0, 0, 0);
        }

        // ---- bias + softmax ----
        float m = -1e30f;
        #pragma unroll
        for (int kt = 0; kt < 20; ++kt) {
            const float4 bv = *(const float4*)(bias + kt * 16 + 4 * gd);
            st[kt][0] += bv.x; st[kt][1] += bv.y; st[kt][2] += bv.z; st[kt][3] += bv.w;
            m = fmaxf(m, fmaxf(fmaxf(st[kt][0], st[kt][1]), fmaxf(st[kt][2], st[kt][3])));
        }
        m = fmaxf(m, __shfl_xor(m, 16, 64));
        m = fmaxf(m, __shfl_xor(m, 32, 64));

        float l = 0.f;
        #pragma unroll
        for (int kt = 0; kt < 20; ++kt) {
            st[kt][0] = __expf(st[kt][0] - m);
            st[kt][1] = __expf(st[kt][1] - m);
            st[kt][2] = __expf(st[kt][2] - m);
            st[kt][3] = __expf(st[kt][3] - m);
            l += st[kt][0] + st[kt][1] + st[kt][2] + st[kt][3];
        }
        l += __shfl_xor(l, 16, 64);
        l += __shfl_xor(l, 32, 64);
        const float inv = 1.0f / l;

        // ---- PV with inline P pack + cross-lane-group bpermute ----
        f32x4 o0 = zero4, o1 = zero4;
        #pragma unroll
        for (int kc = 0; kc < 10; ++kc) {
            const int t0 = 2 * kc, t1 = 2 * kc + 1;
            const unsigned int p01a = pack2(st[t0][0] * inv, st[t0][1] * inv);
            const unsigned int p23a = pack2(st[t0][2] * inv, st[t0][3] * inv);
            const unsigned int p01b = pack2(st[t1][0] * inv, st[t1][1] * inv);
            const unsigned int p23b = pack2(st[t1][2] * inv, st[t1][3] * inv);
            FragU pa;
            {
                const int a0 = __builtin_amdgcn_ds_bpermute(alo, (int)p01a);
                const int b0 = __builtin_amdgcn_ds_bpermute(alo, (int)p01b);
                const int a1 = __builtin_amdgcn_ds_bpermute(alo, (int)p23a);
                const int b1 = __builtin_amdgcn_ds_bpermute(alo, (int)p23b);
                const int a2 = __builtin_amdgcn_ds_bpermute(ahi, (int)p01a);
                const int b2 = __builtin_amdgcn_ds_bpermute(ahi, (int)p01b);
                const int a3 = __builtin_amdgcn_ds_bpermute(ahi, (int)p23a);
                const int b3 = __builtin_amdgcn_ds_bpermute(ahi, (int)p23b);
                pa.u[0] = (unsigned int)(hiT ? b0 : a0);
                pa.u[1] = (unsigned int)(hiT ? b1 : a1);
                pa.u[2] = (unsigned int)(hiT ? b2 : a2);
                pa.u[3] = (unsigned int)(hiT ? b3 : a3);
            }
            FragU bv0, bv1;
            {
                const uint4 x = *(const uint4*)&vT[(0 * 16 + qn) * VSTR + 16 * kc + 4 * gd];
                bv0.u[0] = x.x; bv0.u[1] = x.y; bv0.u[2] = x.z; bv0.u[3] = x.w;
                const uint4 y = *(const uint4*)&vT[(1 * 16 + qn) * VSTR + 16 * kc + 4 * gd];
                bv1.u[0] = y.x; bv1.u[1] = y.y; bv1.u[2] = y.z; bv1.u[3] = y.w;
            }
            o0 = __builtin_amdgcn_mfma_f32_16x16x32_bf16(pa.v, bv0.v, o0, 0, 0, 0);
            o1 = __builtin_amdgcn_mfma_f32_16x16x32_bf16(pa.v, bv1.v, o1, 0, 0, 0);
        }

        #pragma unroll
        for (int r = 0; r < 4; ++r) {
            const int qg = qt * 16 + 4 * gd + r;
            unsigned short* orow = ows + ((size_t)(n * LQ + qg)) * DDIM + h * DHD + qn;
            orow[0]  = f2bf(o0[r]);
            orow[16] = f2bf(o1[r]);
        }
    }
}

// =====================================================================
// K3: out projection + residual (unchanged — near its memory floor).
// =====================================================================
__global__ __launch_bounds__(256) void k3_out(
    const unsigned short* __restrict__ ows, const float* __restrict__ w_out,
    const float* __restrict__ b_out, const float* __restrict__ z,
    float* __restrict__ out)
{
    __shared__ unsigned int wt[128 * 65];  // 33.3 KB
    __shared__ unsigned int ot[64 * 65];   // 16.6 KB
    const int tid = threadIdx.x;
    const int rowbase = blockIdx.x * 64;

    const float2* wp2 = (const float2*)w_out;
    for (int idx = tid; idx < 128 * 64; idx += 256) {
        const int c = idx >> 6, dd = idx & 63;
        const float2 wv = wp2[idx];
        wt[c * 65 + dd] = pack2(wv.x, wv.y);
    }
    const unsigned int* op = (const unsigned int*)ows;
    for (int idx = tid; idx < 64 * 64; idx += 256) {
        const int r = idx >> 6, dd = idx & 63;
        ot[r * 65 + dd] = op[(size_t)(rowbase + r) * 64 + dd];
    }
    __syncthreads();

    const int tx = tid & 15, ty = tid >> 4;
    float acc[4][8];
    #pragma unroll
    for (int j = 0; j < 4; ++j)
        #pragma unroll
        for (int c = 0; c < 8; ++c) acc[j][c] = 0.f;

    #pragma unroll 4
    for (int dd = 0; dd < 64; ++dd) {
        float ax[4], ay[4];
        #pragma unroll
        for (int j = 0; j < 4; ++j) {
            const unsigned int u = ot[(4 * ty + j) * 65 + dd];
            ax[j] = bf_lo(u); ay[j] = bf_hi(u);
        }
        #pragma unroll
        for (int c = 0; c < 8; ++c) {
            const unsigned int u = wt[(tx + 16 * c) * 65 + dd];
            const float wx = bf_lo(u), wy = bf_hi(u);
            #pragma unroll
            for (int j = 0; j < 4; ++j) acc[j][c] += ax[j] * wx + ay[j] * wy;
        }
    }

    #pragma unroll
    for (int j = 0; j < 4; ++j) {
        const int row = rowbase + 4 * ty + j;
        const float* zr = z + (size_t)row * DDIM;
        float* outr = out + (size_t)row * DDIM;
        #pragma unroll
        for (int c = 0; c < 8; ++c) {
            const int cg = tx + 16 * c;
            outr[cg] = acc[j][c] + b_out[cg] + zr[cg];
        }
    }
}

extern "C" void kernel_launch(void* const* d_in, const int* in_sizes, int n_in,
                              void* d_out, int out_size, void* d_ws, size_t ws_size,
                              hipStream_t stream) {
    const float* z     = (const float*)d_in[0];
    const int*   mask  = (const int*)d_in[1];
    const float* ln_g  = (const float*)d_in[2];
    const float* ln_b  = (const float*)d_in[3];
    const float* w_qkv = (const float*)d_in[4];
    const float* b_qkv = (const float*)d_in[5];
    const float* w_out = (const float*)d_in[6];
    const float* b_out = (const float*)d_in[7];
    float* out = (float*)d_out;

    // ws layout (bf16): q [n][h][i][d], k [n][h][i][d], v TRANSPOSED [n][h][d][i], o [row][D]
    unsigned short* ws = (unsigned short*)d_ws;
    const size_t qE = (size_t)NSEQ * NH * LQ * DHD;  // 13,107,200
    unsigned short* qws = ws;
    unsigned short* kws = qws + qE;
    unsigned short* vws = kws + qE;
    unsigned short* ows = vws + qE;  // NROWS * DDIM

    hipLaunchKernelGGL(k1_ln_qkv, dim3(NROWS / 64), dim3(256), 0, stream,
                       z, ln_g, ln_b, w_qkv, b_qkv, qws, kws, vws);
    hipLaunchKernelGGL(k2_attn_mfma, dim3(NSEQ * NH), dim3(256), 0, stream,
                       qws, kws, vws, mask, ows);
    hipLaunchKernelGGL(k3_out, dim3(NROWS / 64), dim3(256), 0, stream,
                       ows, w_out, b_out, z, out);
}

// Round 4
// 312.455 us; speedup vs baseline: 3.9928x; 1.4910x over previous
//
#include <hip/hip_runtime.h>

// Problem constants: B=1, L=320, D=128, H=4, DH=32
#define LQ 320
#define NSEQ 320
#define NROWS (NSEQ*LQ)   // 102400
#define DDIM 128
#define NH 4
#define DHD 32
#define LN_EPS 1e-5f
#define QSCALE 0.17677669529663687f  // 1/sqrt(32), folded into q at K1 epilogue

typedef __bf16 bf16x8 __attribute__((ext_vector_type(8)));
typedef float f32x4 __attribute__((ext_vector_type(4)));
union FragU { unsigned int u[4]; bf16x8 v; };

__device__ inline float bf_lo(unsigned int u) { return __uint_as_float(u << 16); }
__device__ inline float bf_hi(unsigned int u) { return __uint_as_float(u & 0xffff0000u); }
__device__ inline unsigned short f2bf(float f) {
    unsigned int u = __float_as_uint(f);
    u += 0x7fffu + ((u >> 16) & 1u);
    return (unsigned short)(u >> 16);
}
__device__ inline unsigned int pack2(float a, float b) {
    return (unsigned int)f2bf(a) | ((unsigned int)f2bf(b) << 16);
}

// =====================================================================
// K0: LayerNorm -> zn bf16 [row][128] in ws. Grid 1600, block 256.
// Each wave handles 16 rows; lane holds cols 2*lane, 2*lane+1.
// Memory-bound: 52.4 MB read + 26.2 MB write.
// =====================================================================
__global__ __launch_bounds__(256) void k0_ln(
    const float* __restrict__ z, const float* __restrict__ ln_g, const float* __restrict__ ln_b,
    unsigned int* __restrict__ znws)
{
    const int tid = threadIdx.x;
    const int rowbase = blockIdx.x * 64;
    const int lane = tid & 63;
    const int wid = tid >> 6;
    const float g0 = ln_g[2 * lane], g1 = ln_g[2 * lane + 1];
    const float bb0 = ln_b[2 * lane], bb1 = ln_b[2 * lane + 1];
    #pragma unroll 1
    for (int r = wid; r < 64; r += 4) {
        const int row = rowbase + r;
        const float2 v = *(const float2*)(z + (size_t)row * DDIM + 2 * lane);
        float s = v.x + v.y;
        float s2 = v.x * v.x + v.y * v.y;
        #pragma unroll
        for (int off = 32; off > 0; off >>= 1) {
            s  += __shfl_xor(s, off, 64);
            s2 += __shfl_xor(s2, off, 64);
        }
        const float mu = s * (1.0f / 128.0f);
        const float var = s2 * (1.0f / 128.0f) - mu * mu;
        const float rs = rsqrtf(var + LN_EPS);
        znws[(size_t)row * 64 + lane] =
            pack2((v.x - mu) * rs * g0 + bb0, (v.y - mu) * rs * g1 + bb1);
    }
}

// =====================================================================
// K1: QKV GEMM, 3-way N-split. Grid 2400 (sect = bx%3, m = bx/3), block 256.
// Block tile: M=128 rows x N=128 cols (sect picks q/k/v). K=128.
// LDS: W chunk bf16 [128][68] 34.8KB + zn [128][68] 34.8KB = 69.7KB -> 2 blocks/CU.
// Wave tile: M=32 (2 rowgroups) x N=128 (8 ntiles), 64 MFMA/wave.
// sect 0/1 (q/k): direct coalesced-ish stores. sect 2 (v): transpose
// through LDS (reusing wlds) so [d][i] stores are 8B-contiguous runs.
// =====================================================================
__global__ __launch_bounds__(256) void k1_qkv(
    const unsigned int* __restrict__ znws, const float* __restrict__ w_qkv,
    const float* __restrict__ b_qkv,
    unsigned short* __restrict__ qws, unsigned short* __restrict__ kws,
    unsigned short* __restrict__ vws)
{
    __shared__ unsigned int wlds[128 * 68];  // 34816 B (also reused as transpose buf)
    __shared__ unsigned int znb[128 * 68];   // 34816 B
    const int tid = threadIdx.x;
    const int bx = blockIdx.x;
    const int sect = bx % 3;          // 0=q 1=k 2=v
    const int mbase = (bx / 3) * 128;
    const int lane = tid & 63;
    const int wid = tid >> 6;
    const int qn = lane & 15, gd = lane >> 4;

    // stage W chunk (fp32 -> bf16): rows sect*128..+127
    const float4* wp4 = (const float4*)w_qkv;
    #pragma unroll 1
    for (int idx = tid; idx < 128 * 32; idx += 256) {
        const int row = idx >> 5, c4 = idx & 31;
        const float4 w4 = wp4[(size_t)(sect * 128 + row) * 32 + c4];
        wlds[row * 68 + 2 * c4]     = pack2(w4.x, w4.y);
        wlds[row * 68 + 2 * c4 + 1] = pack2(w4.z, w4.w);
    }
    // stage zn tile (already bf16): rows mbase..+127
    const uint4* zp4 = (const uint4*)znws;
    #pragma unroll 1
    for (int idx = tid; idx < 128 * 16; idx += 256) {
        const int row = idx >> 4, c = idx & 15;
        *(uint4*)&znb[row * 68 + 4 * c] = zp4[(size_t)(mbase + row) * 16 + c];
    }
    __syncthreads();

    const f32x4 zero4 = {0.f, 0.f, 0.f, 0.f};
    f32x4 acc[2][8];
    #pragma unroll
    for (int rg = 0; rg < 2; ++rg)
        #pragma unroll
        for (int nt = 0; nt < 8; ++nt) acc[rg][nt] = zero4;

    #pragma unroll
    for (int kt = 0; kt < 4; ++kt) {
        FragU af[2];
        #pragma unroll
        for (int rg = 0; rg < 2; ++rg)
            af[rg].v = *(const bf16x8*)&znb[(wid * 32 + rg * 16 + qn) * 68 + 16 * kt + 4 * gd];
        #pragma unroll
        for (int nt = 0; nt < 8; ++nt) {
            FragU bf;
            bf.v = *(const bf16x8*)&wlds[(nt * 16 + qn) * 68 + 16 * kt + 4 * gd];
            #pragma unroll
            for (int rg = 0; rg < 2; ++rg)
                acc[rg][nt] = __builtin_amdgcn_mfma_f32_16x16x32_bf16(af[rg].v, bf.v, acc[rg][nt], 0, 0, 0);
        }
    }

    float bq[8];
    #pragma unroll
    for (int nt = 0; nt < 8; ++nt) bq[nt] = b_qkv[sect * 128 + nt * 16 + qn];

    if (sect < 2) {
        unsigned short* dst = (sect == 0) ? qws : kws;
        const float sc = (sect == 0) ? QSCALE : 1.0f;
        #pragma unroll
        for (int rg = 0; rg < 2; ++rg) {
            #pragma unroll
            for (int r = 0; r < 4; ++r) {
                const int grow = mbase + wid * 32 + rg * 16 + 4 * gd + r;
                const int n = grow / LQ;
                const int i = grow - n * LQ;
                #pragma unroll
                for (int nt = 0; nt < 8; ++nt) {
                    const int cg = nt * 16 + qn;          // 0..127
                    const int hh = cg >> 5, d = cg & 31;
                    dst[((size_t)((n * NH + hh) * LQ + i)) * DHD + d] =
                        f2bf((acc[rg][nt][r] + bq[nt]) * sc);
                }
            }
        }
    } else {
        // v: transpose via LDS (reuse wlds as ushort [128 col][132])
        __syncthreads();   // all waves done reading wlds frags
        unsigned short* tr = (unsigned short*)wlds;
        #pragma unroll
        for (int rg = 0; rg < 2; ++rg) {
            #pragma unroll
            for (int r = 0; r < 4; ++r) {
                const int row = wid * 32 + rg * 16 + 4 * gd + r;
                #pragma unroll
                for (int nt = 0; nt < 8; ++nt) {
                    const int col = nt * 16 + qn;
                    tr[col * 132 + row] = f2bf(acc[rg][nt][r] + bq[nt]);
                }
            }
        }
        __syncthreads();
        // write out: thread -> (col, iseg); 64 rows each, 8B vector stores
        const int col = tid >> 1, iseg = tid & 1;
        const int hh = col >> 5, d = col & 31;
        #pragma unroll
        for (int t = 0; t < 16; ++t) {
            const int row = iseg * 64 + 4 * t;
            const int grow = mbase + row;
            const int n = grow / LQ;
            const int i = grow - n * LQ;   // i%4==0, 320%4==0 -> no n-split inside ushort4
            const ushort4 val = *(const ushort4*)&tr[col * 132 + row];
            *(ushort4*)&vws[((size_t)((n * NH + hh) * DHD + d)) * LQ + i] = val;
        }
    }
}

// =====================================================================
// K2: MFMA attention. Grid 1280 (block per n,h), 256 threads (4 waves).
// Round-4: V B-frags read DIRECTLY from global (16B coalesced, 20KB/head,
// L1/L2-resident) -> LDS drops 47.9 -> 26.9 KB -> 5 blocks/CU.
// =====================================================================
#define KSTR 20
__global__ __launch_bounds__(256) void k2_attn_mfma(
    const unsigned short* __restrict__ qws, const unsigned short* __restrict__ kws,
    const unsigned short* __restrict__ vtws, const int* __restrict__ mask,
    unsigned short* __restrict__ ows)
{
    __shared__ unsigned int kT[LQ * KSTR];   // 25.6 KB
    __shared__ float bias[LQ];               // 1.25 KB
    const int tid = threadIdx.x;
    const int nh = blockIdx.x;
    const int lane = tid & 63;
    const int wid = tid >> 6;
    const int qn = lane & 15;
    const int gd = lane >> 4;

    const unsigned int* kp = (const unsigned int*)kws + (size_t)nh * LQ * 16;
    #pragma unroll 1
    for (int idx = tid; idx < LQ * 16; idx += 256) {
        const int r = idx >> 4, c = idx & 15;
        kT[r * KSTR + c] = kp[idx];
    }
    for (int i = tid; i < LQ; i += 256) bias[i] = (mask[i] > 0) ? 0.f : -1e30f;
    __syncthreads();

    const f32x4 zero4 = {0.f, 0.f, 0.f, 0.f};
    const int alo = (((gd & 1) << 5) | qn) << 2;
    const int ahi = alo + 64;
    const bool hiT = (gd >= 2);
    const int n = nh >> 2, h = nh & 3;
    const unsigned short* vbase = vtws + (size_t)nh * DHD * LQ;  // [32][320] bf16

    #pragma unroll 1
    for (int it = 0; it < 5; ++it) {
        const int qt = wid * 5 + it;

        FragU qf;
        qf.v = *(const bf16x8*)(qws + ((size_t)nh * LQ + qt * 16 + qn) * DHD + 8 * gd);

        // ---- QK^T: 20 S^T tiles ----
        f32x4 st[20];
        #pragma unroll
        for (int kt = 0; kt < 20; ++kt) {
            const unsigned int* kptr = &kT[(kt * 16 + qn) * KSTR + 4 * gd];
            FragU kf;
            const uint2 ka = *(const uint2*)kptr;
            const uint2 kb = *(const uint2*)(kptr + 2);
            kf.u[0] = ka.x; kf.u[1] = ka.y; kf.u[2] = kb.x; kf.u[3] = kb.y;
            st[kt] = __builtin_amdgcn_mfma_f32_16x16x32_bf16(kf.v, qf.v, zero4, 0, 0, 0);
        }

        // ---- bias + softmax ----
        float m = -1e30f;
        #pragma unroll
        for (int kt = 0; kt < 20; ++kt) {
            const float4 bv = *(const float4*)(bias + kt * 16 + 4 * gd);
            st[kt][0] += bv.x; st[kt][1] += bv.y; st[kt][2] += bv.z; st[kt][3] += bv.w;
            m = fmaxf(m, fmaxf(fmaxf(st[kt][0], st[kt][1]), fmaxf(st[kt][2], st[kt][3])));
        }
        m = fmaxf(m, __shfl_xor(m, 16, 64));
        m = fmaxf(m, __shfl_xor(m, 32, 64));

        float l = 0.f;
        #pragma unroll
        for (int kt = 0; kt < 20; ++kt) {
            st[kt][0] = __expf(st[kt][0] - m);
            st[kt][1] = __expf(st[kt][1] - m);
            st[kt][2] = __expf(st[kt][2] - m);
            st[kt][3] = __expf(st[kt][3] - m);
            l += st[kt][0] + st[kt][1] + st[kt][2] + st[kt][3];
        }
        l += __shfl_xor(l, 16, 64);
        l += __shfl_xor(l, 32, 64);
        const float inv = 1.0f / l;

        // ---- PV: inline P pack + bpermute; V frags from global ----
        f32x4 o0 = zero4, o1 = zero4;
        #pragma unroll
        for (int kc = 0; kc < 10; ++kc) {
            const int t0 = 2 * kc, t1 = 2 * kc + 1;
            const unsigned int p01a = pack2(st[t0][0] * inv, st[t0][1] * inv);
            const unsigned int p23a = pack2(st[t0][2] * inv, st[t0][3] * inv);
            const unsigned int p01b = pack2(st[t1][0] * inv, st[t1][1] * inv);
            const unsigned int p23b = pack2(st[t1][2] * inv, st[t1][3] * inv);
            FragU pa;
            {
                const int a0 = __builtin_amdgcn_ds_bpermute(alo, (int)p01a);
                const int b0 = __builtin_amdgcn_ds_bpermute(alo, (int)p01b);
                const int a1 = __builtin_amdgcn_ds_bpermute(alo, (int)p23a);
                const int b1 = __builtin_amdgcn_ds_bpermute(alo, (int)p23b);
                const int a2 = __builtin_amdgcn_ds_bpermute(ahi, (int)p01a);
                const int b2 = __builtin_amdgcn_ds_bpermute(ahi, (int)p01b);
                const int a3 = __builtin_amdgcn_ds_bpermute(ahi, (int)p23a);
                const int b3 = __builtin_amdgcn_ds_bpermute(ahi, (int)p23b);
                pa.u[0] = (unsigned int)(hiT ? b0 : a0);
                pa.u[1] = (unsigned int)(hiT ? b1 : a1);
                pa.u[2] = (unsigned int)(hiT ? b2 : a2);
                pa.u[3] = (unsigned int)(hiT ? b3 : a3);
            }
            FragU bv0, bv1;
            bv0.v = *(const bf16x8*)(vbase + (0 * 16 + qn) * LQ + 32 * kc + 8 * gd);
            bv1.v = *(const bf16x8*)(vbase + (1 * 16 + qn) * LQ + 32 * kc + 8 * gd);
            o0 = __builtin_amdgcn_mfma_f32_16x16x32_bf16(pa.v, bv0.v, o0, 0, 0, 0);
            o1 = __builtin_amdgcn_mfma_f32_16x16x32_bf16(pa.v, bv1.v, o1, 0, 0, 0);
        }

        #pragma unroll
        for (int r = 0; r < 4; ++r) {
            const int qg = qt * 16 + 4 * gd + r;
            unsigned short* orow = ows + ((size_t)(n * LQ + qg)) * DDIM + h * DHD + qn;
            orow[0]  = f2bf(o0[r]);
            orow[16] = f2bf(o1[r]);
        }
    }
}

// =====================================================================
// K3: out projection + residual, MFMA. Grid 800, block 256.
// Block tile: M=128 x N=128, K=128. LDS: w_out bf16 [128][68] + o [128][68]
// = 69.7 KB -> 2 blocks/CU. Epilogue fuses b_out + z residual, fp32 stores.
// =====================================================================
__global__ __launch_bounds__(256) void k3_out(
    const unsigned short* __restrict__ ows, const float* __restrict__ w_out,
    const float* __restrict__ b_out, const float* __restrict__ z,
    float* __restrict__ out)
{
    __shared__ unsigned int wlds[128 * 68];
    __shared__ unsigned int ob[128 * 68];
    const int tid = threadIdx.x;
    const int mbase = blockIdx.x * 128;
    const int lane = tid & 63;
    const int wid = tid >> 6;
    const int qn = lane & 15, gd = lane >> 4;

    const float4* wp4 = (const float4*)w_out;
    #pragma unroll 1
    for (int idx = tid; idx < 128 * 32; idx += 256) {
        const int row = idx >> 5, c4 = idx & 31;
        const float4 w4 = wp4[idx];
        wlds[row * 68 + 2 * c4]     = pack2(w4.x, w4.y);
        wlds[row * 68 + 2 * c4 + 1] = pack2(w4.z, w4.w);
    }
    const uint4* op4 = (const uint4*)ows;
    #pragma unroll 1
    for (int idx = tid; idx < 128 * 16; idx += 256) {
        const int row = idx >> 4, c = idx & 15;
        *(uint4*)&ob[row * 68 + 4 * c] = op4[(size_t)(mbase + row) * 16 + c];
    }
    __syncthreads();

    const f32x4 zero4 = {0.f, 0.f, 0.f, 0.f};
    f32x4 acc[2][8];
    #pragma unroll
    for (int rg = 0; rg < 2; ++rg)
        #pragma unroll
        for (int nt = 0; nt < 8; ++nt) acc[rg][nt] = zero4;

    #pragma unroll
    for (int kt = 0; kt < 4; ++kt) {
        FragU af[2];
        #pragma unroll
        for (int rg = 0; rg < 2; ++rg)
            af[rg].v = *(const bf16x8*)&ob[(wid * 32 + rg * 16 + qn) * 68 + 16 * kt + 4 * gd];
        #pragma unroll
        for (int nt = 0; nt < 8; ++nt) {
            FragU bf;
            bf.v = *(const bf16x8*)&wlds[(nt * 16 + qn) * 68 + 16 * kt + 4 * gd];
            #pragma unroll
            for (int rg = 0; rg < 2; ++rg)
                acc[rg][nt] = __builtin_amdgcn_mfma_f32_16x16x32_bf16(af[rg].v, bf.v, acc[rg][nt], 0, 0, 0);
        }
    }

    float bb[8];
    #pragma unroll
    for (int nt = 0; nt < 8; ++nt) bb[nt] = b_out[nt * 16 + qn];

    #pragma unroll
    for (int rg = 0; rg < 2; ++rg) {
        #pragma unroll
        for (int r = 0; r < 4; ++r) {
            const int grow = mbase + wid * 32 + rg * 16 + 4 * gd + r;
            const float* zr = z + (size_t)grow * DDIM;
            float* outr = out + (size_t)grow * DDIM;
            #pragma unroll
            for (int nt = 0; nt < 8; ++nt) {
                const int cg = nt * 16 + qn;
                outr[cg] = acc[rg][nt][r] + bb[nt] + zr[cg];
            }
        }
    }
}

extern "C" void kernel_launch(void* const* d_in, const int* in_sizes, int n_in,
                              void* d_out, int out_size, void* d_ws, size_t ws_size,
                              hipStream_t stream) {
    const float* z     = (const float*)d_in[0];
    const int*   mask  = (const int*)d_in[1];
    const float* ln_g  = (const float*)d_in[2];
    const float* ln_b  = (const float*)d_in[3];
    const float* w_qkv = (const float*)d_in[4];
    const float* b_qkv = (const float*)d_in[5];
    const float* w_out = (const float*)d_in[6];
    const float* b_out = (const float*)d_in[7];
    float* out = (float*)d_out;

    // ws (bf16): q [nh][i][d], k [nh][i][d], v [nh][d][i], then a shared
    // region aliased as zn [row][128] (K0->K1) and o [row][128] (K2->K3) —
    // lifetimes are disjoint, sizes identical (26.2 MB). Total 105 MB.
    unsigned short* ws = (unsigned short*)d_ws;
    const size_t qE = (size_t)NSEQ * NH * LQ * DHD;  // 13,107,200
    unsigned short* qws = ws;
    unsigned short* kws = qws + qE;
    unsigned short* vws = kws + qE;
    unsigned short* shared_rgn = vws + qE;           // NROWS*DDIM bf16
    unsigned int*   znws = (unsigned int*)shared_rgn;
    unsigned short* ows  = shared_rgn;

    hipLaunchKernelGGL(k0_ln, dim3(NROWS / 64), dim3(256), 0, stream,
                       z, ln_g, ln_b, znws);
    hipLaunchKernelGGL(k1_qkv, dim3(2400), dim3(256), 0, stream,
                       znws, w_qkv, b_qkv, qws, kws, vws);
    hipLaunchKernelGGL(k2_attn_mfma, dim3(NSEQ * NH), dim3(256), 0, stream,
                       qws, kws, vws, mask, ows);
    hipLaunchKernelGGL(k3_out, dim3(800), dim3(256), 0, stream,
                       ows, w_out, b_out, z, out);
}

// Round 5
// 277.009 us; speedup vs baseline: 4.5037x; 1.1280x over previous
//
#include <hip/hip_runtime.h>

// Problem constants: B=1, L=320, D=128, H=4, DH=32
#define LQ 320
#define NSEQ 320
#define NROWS (NSEQ*LQ)   // 102400
#define DDIM 128
#define NH 4
#define DHD 32
#define LN_EPS 1e-5f
// 1/sqrt(32) * log2(e): folded into q so QK^T scores are in log2 domain
#define QSC2 0.25508652025545527f

typedef __bf16 bf16x8 __attribute__((ext_vector_type(8)));
typedef float f32x4 __attribute__((ext_vector_type(4)));
union FragU { unsigned int u[4]; bf16x8 v; };

__device__ inline float bf_lo(unsigned int u) { return __uint_as_float(u << 16); }
__device__ inline float bf_hi(unsigned int u) { return __uint_as_float(u & 0xffff0000u); }
__device__ inline unsigned short f2bf(float f) {
    unsigned int u = __float_as_uint(f);
    u += 0x7fffu + ((u >> 16) & 1u);
    return (unsigned short)(u >> 16);
}
__device__ inline unsigned int pack2(float a, float b) {
    return (unsigned int)f2bf(a) | ((unsigned int)f2bf(b) << 16);
}

// =====================================================================
// K0: LayerNorm -> zn bf16 [row][128] in ws. Grid 1600, block 256.
// =====================================================================
__global__ __launch_bounds__(256) void k0_ln(
    const float* __restrict__ z, const float* __restrict__ ln_g, const float* __restrict__ ln_b,
    unsigned int* __restrict__ znws)
{
    const int tid = threadIdx.x;
    const int rowbase = blockIdx.x * 64;
    const int lane = tid & 63;
    const int wid = tid >> 6;
    const float g0 = ln_g[2 * lane], g1 = ln_g[2 * lane + 1];
    const float bb0 = ln_b[2 * lane], bb1 = ln_b[2 * lane + 1];
    #pragma unroll 1
    for (int r = wid; r < 64; r += 4) {
        const int row = rowbase + r;
        const float2 v = *(const float2*)(z + (size_t)row * DDIM + 2 * lane);
        float s = v.x + v.y;
        float s2 = v.x * v.x + v.y * v.y;
        #pragma unroll
        for (int off = 32; off > 0; off >>= 1) {
            s  += __shfl_xor(s, off, 64);
            s2 += __shfl_xor(s2, off, 64);
        }
        const float mu = s * (1.0f / 128.0f);
        const float var = s2 * (1.0f / 128.0f) - mu * mu;
        const float rs = rsqrtf(var + LN_EPS);
        znws[(size_t)row * 64 + lane] =
            pack2((v.x - mu) * rs * g0 + bb0, (v.y - mu) * rs * g1 + bb1);
    }
}

// =====================================================================
// K1: QKV GEMM, 3-way N-split. Grid 2400 (sect = bx%3, m = bx/3), block 256.
// LDS: W chunk bf16 [128][68] + zn [128][68] = 69.7KB -> 2 blocks/CU.
// q prescaled by 1/sqrt(DH)*log2e (K2 does exp2); v stored transposed.
// =====================================================================
__global__ __launch_bounds__(256) void k1_qkv(
    const unsigned int* __restrict__ znws, const float* __restrict__ w_qkv,
    const float* __restrict__ b_qkv,
    unsigned short* __restrict__ qws, unsigned short* __restrict__ kws,
    unsigned short* __restrict__ vws)
{
    __shared__ unsigned int wlds[128 * 68];
    __shared__ unsigned int znb[128 * 68];
    const int tid = threadIdx.x;
    const int bx = blockIdx.x;
    const int sect = bx % 3;          // 0=q 1=k 2=v
    const int mbase = (bx / 3) * 128;
    const int lane = tid & 63;
    const int wid = tid >> 6;
    const int qn = lane & 15, gd = lane >> 4;

    const float4* wp4 = (const float4*)w_qkv;
    #pragma unroll 1
    for (int idx = tid; idx < 128 * 32; idx += 256) {
        const int row = idx >> 5, c4 = idx & 31;
        const float4 w4 = wp4[(size_t)(sect * 128 + row) * 32 + c4];
        wlds[row * 68 + 2 * c4]     = pack2(w4.x, w4.y);
        wlds[row * 68 + 2 * c4 + 1] = pack2(w4.z, w4.w);
    }
    const uint4* zp4 = (const uint4*)znws;
    #pragma unroll 1
    for (int idx = tid; idx < 128 * 16; idx += 256) {
        const int row = idx >> 4, c = idx & 15;
        *(uint4*)&znb[row * 68 + 4 * c] = zp4[(size_t)(mbase + row) * 16 + c];
    }
    __syncthreads();

    const f32x4 zero4 = {0.f, 0.f, 0.f, 0.f};
    f32x4 acc[2][8];
    #pragma unroll
    for (int rg = 0; rg < 2; ++rg)
        #pragma unroll
        for (int nt = 0; nt < 8; ++nt) acc[rg][nt] = zero4;

    #pragma unroll
    for (int kt = 0; kt < 4; ++kt) {
        FragU af[2];
        #pragma unroll
        for (int rg = 0; rg < 2; ++rg)
            af[rg].v = *(const bf16x8*)&znb[(wid * 32 + rg * 16 + qn) * 68 + 16 * kt + 4 * gd];
        #pragma unroll
        for (int nt = 0; nt < 8; ++nt) {
            FragU bf;
            bf.v = *(const bf16x8*)&wlds[(nt * 16 + qn) * 68 + 16 * kt + 4 * gd];
            #pragma unroll
            for (int rg = 0; rg < 2; ++rg)
                acc[rg][nt] = __builtin_amdgcn_mfma_f32_16x16x32_bf16(af[rg].v, bf.v, acc[rg][nt], 0, 0, 0);
        }
    }

    float bq[8];
    #pragma unroll
    for (int nt = 0; nt < 8; ++nt) bq[nt] = b_qkv[sect * 128 + nt * 16 + qn];

    if (sect < 2) {
        unsigned short* dst = (sect == 0) ? qws : kws;
        const float sc = (sect == 0) ? QSC2 : 1.0f;
        #pragma unroll
        for (int rg = 0; rg < 2; ++rg) {
            #pragma unroll
            for (int r = 0; r < 4; ++r) {
                const int grow = mbase + wid * 32 + rg * 16 + 4 * gd + r;
                const int n = grow / LQ;
                const int i = grow - n * LQ;
                #pragma unroll
                for (int nt = 0; nt < 8; ++nt) {
                    const int cg = nt * 16 + qn;
                    const int hh = cg >> 5, d = cg & 31;
                    dst[((size_t)((n * NH + hh) * LQ + i)) * DHD + d] =
                        f2bf((acc[rg][nt][r] + bq[nt]) * sc);
                }
            }
        }
    } else {
        __syncthreads();
        unsigned short* tr = (unsigned short*)wlds;
        #pragma unroll
        for (int rg = 0; rg < 2; ++rg) {
            #pragma unroll
            for (int r = 0; r < 4; ++r) {
                const int row = wid * 32 + rg * 16 + 4 * gd + r;
                #pragma unroll
                for (int nt = 0; nt < 8; ++nt) {
                    const int col = nt * 16 + qn;
                    tr[col * 132 + row] = f2bf(acc[rg][nt][r] + bq[nt]);
                }
            }
        }
        __syncthreads();
        const int col = tid >> 1, iseg = tid & 1;
        const int hh = col >> 5, d = col & 31;
        #pragma unroll
        for (int t = 0; t < 16; ++t) {
            const int row = iseg * 64 + 4 * t;
            const int grow = mbase + row;
            const int n = grow / LQ;
            const int i = grow - n * LQ;
            const ushort4 val = *(const ushort4*)&tr[col * 132 + row];
            *(ushort4*)&vws[((size_t)((n * NH + hh) * DHD + d)) * LQ + i] = val;
        }
    }
}

// =====================================================================
// K2: MFMA attention, round-5. Grid 1280 (block per n,h), 256 thr (4 waves).
// Occupancy fix: online softmax over two 160-key halves (st[10] live, not
// st[20]); __launch_bounds__(256,4) targets <=128 VGPR -> 4 waves/SIMD.
// VALU diet: bias folded into MFMA C operand; scores in log2 domain
// (q prescaled by log2e/sqrt(DH), v_exp2 only); unnormalized-P PV with a
// single 1/l at the end. K-frags via single ds_read_b128 (uniform banks
// at 80B row stride).
// LDS: kT [320][20] 25.6KB + bias 1.25KB. V frags direct from global (L2).
// =====================================================================
#define KSTR 20
__global__ __launch_bounds__(256, 4) void k2_attn_mfma(
    const unsigned short* __restrict__ qws, const unsigned short* __restrict__ kws,
    const unsigned short* __restrict__ vtws, const int* __restrict__ mask,
    unsigned short* __restrict__ ows)
{
    __shared__ unsigned int kT[LQ * KSTR];        // 25.6 KB
    __shared__ __align__(16) float bias[LQ];      // 1.25 KB
    const int tid = threadIdx.x;
    const int nh = blockIdx.x;
    const int lane = tid & 63;
    const int wid = tid >> 6;
    const int qn = lane & 15;
    const int gd = lane >> 4;

    // stage K via b128: [320 rows][16 uints] -> [320][KSTR]
    const uint4* kp4 = (const uint4*)(kws + (size_t)nh * LQ * DHD);
    #pragma unroll 1
    for (int idx = tid; idx < LQ * 4; idx += 256) {
        const int r = idx >> 2, c4 = idx & 3;
        *(uint4*)&kT[r * KSTR + 4 * c4] = kp4[idx];
    }
    for (int i = tid; i < LQ; i += 256) bias[i] = (mask[i] > 0) ? 0.f : -1e30f;
    __syncthreads();

    const f32x4 zero4 = {0.f, 0.f, 0.f, 0.f};
    const int alo = (((gd & 1) << 5) | qn) << 2;
    const int ahi = alo + 64;
    const bool hiT = (gd >= 2);
    const int n = nh >> 2, h = nh & 3;
    const unsigned short* vbase = vtws + (size_t)nh * DHD * LQ;  // [32][320] bf16

    #pragma unroll 1
    for (int it = 0; it < 5; ++it) {
        const int qt = wid * 5 + it;

        FragU qf;
        qf.v = *(const bf16x8*)(qws + ((size_t)nh * LQ + qt * 16 + qn) * DHD + 8 * gd);

        f32x4 o0 = zero4, o1 = zero4;
        float m_run = -1e30f;
        float l_run = 0.f;   // per-lane partial (this lane's keys only)

        #pragma unroll 1
        for (int half = 0; half < 2; ++half) {
            const int tb = half * 10;

            // ---- QK^T: 10 S^T tiles, bias pre-loaded as C ----
            f32x4 st[10];
            #pragma unroll
            for (int kt = 0; kt < 10; ++kt) {
                const int ktg = tb + kt;
                FragU kf;
                const uint4 kv = *(const uint4*)&kT[(ktg * 16 + qn) * KSTR + 4 * gd];
                kf.u[0] = kv.x; kf.u[1] = kv.y; kf.u[2] = kv.z; kf.u[3] = kv.w;
                const f32x4 c0 = *(const f32x4*)&bias[ktg * 16 + 4 * gd];
                st[kt] = __builtin_amdgcn_mfma_f32_16x16x32_bf16(kf.v, qf.v, c0, 0, 0, 0);
            }

            // ---- online softmax update (log2 domain) ----
            float mh = -1e30f;
            #pragma unroll
            for (int kt = 0; kt < 10; ++kt)
                mh = fmaxf(mh, fmaxf(fmaxf(st[kt][0], st[kt][1]), fmaxf(st[kt][2], st[kt][3])));
            mh = fmaxf(mh, __shfl_xor(mh, 16, 64));
            mh = fmaxf(mh, __shfl_xor(mh, 32, 64));
            const float m_new = fmaxf(m_run, mh);
            const float sc = __builtin_amdgcn_exp2f(m_run - m_new);  // 0 on first half
            m_run = m_new;
            l_run *= sc;
            o0 *= sc;
            o1 *= sc;

            #pragma unroll
            for (int kt = 0; kt < 10; ++kt) {
                st[kt][0] = __builtin_amdgcn_exp2f(st[kt][0] - m_new);
                st[kt][1] = __builtin_amdgcn_exp2f(st[kt][1] - m_new);
                st[kt][2] = __builtin_amdgcn_exp2f(st[kt][2] - m_new);
                st[kt][3] = __builtin_amdgcn_exp2f(st[kt][3] - m_new);
                l_run += st[kt][0] + st[kt][1] + st[kt][2] + st[kt][3];
            }

            // ---- PV (unnormalized P) ----
            #pragma unroll
            for (int kc = 0; kc < 5; ++kc) {
                const int t0 = 2 * kc, t1 = 2 * kc + 1;
                const unsigned int p01a = pack2(st[t0][0], st[t0][1]);
                const unsigned int p23a = pack2(st[t0][2], st[t0][3]);
                const unsigned int p01b = pack2(st[t1][0], st[t1][1]);
                const unsigned int p23b = pack2(st[t1][2], st[t1][3]);
                FragU pa;
                {
                    const int a0 = __builtin_amdgcn_ds_bpermute(alo, (int)p01a);
                    const int b0 = __builtin_amdgcn_ds_bpermute(alo, (int)p01b);
                    const int a1 = __builtin_amdgcn_ds_bpermute(alo, (int)p23a);
                    const int b1 = __builtin_amdgcn_ds_bpermute(alo, (int)p23b);
                    const int a2 = __builtin_amdgcn_ds_bpermute(ahi, (int)p01a);
                    const int b2 = __builtin_amdgcn_ds_bpermute(ahi, (int)p01b);
                    const int a3 = __builtin_amdgcn_ds_bpermute(ahi, (int)p23a);
                    const int b3 = __builtin_amdgcn_ds_bpermute(ahi, (int)p23b);
                    pa.u[0] = (unsigned int)(hiT ? b0 : a0);
                    pa.u[1] = (unsigned int)(hiT ? b1 : a1);
                    pa.u[2] = (unsigned int)(hiT ? b2 : a2);
                    pa.u[3] = (unsigned int)(hiT ? b3 : a3);
                }
                FragU bv0, bv1;
                const int koff = half * 160 + 32 * kc + 8 * gd;
                bv0.v = *(const bf16x8*)(vbase + (0 * 16 + qn) * LQ + koff);
                bv1.v = *(const bf16x8*)(vbase + (1 * 16 + qn) * LQ + koff);
                o0 = __builtin_amdgcn_mfma_f32_16x16x32_bf16(pa.v, bv0.v, o0, 0, 0, 0);
                o1 = __builtin_amdgcn_mfma_f32_16x16x32_bf16(pa.v, bv1.v, o1, 0, 0, 0);
            }
        }

        // full-row l and final normalize
        l_run += __shfl_xor(l_run, 16, 64);
        l_run += __shfl_xor(l_run, 32, 64);
        const float inv = 1.0f / l_run;

        #pragma unroll
        for (int r = 0; r < 4; ++r) {
            const int qg = qt * 16 + 4 * gd + r;
            unsigned short* orow = ows + ((size_t)(n * LQ + qg)) * DDIM + h * DHD + qn;
            orow[0]  = f2bf(o0[r] * inv);
            orow[16] = f2bf(o1[r] * inv);
        }
    }
}

// =====================================================================
// K3: out projection + residual, MFMA. Grid 800, block 256. (unchanged)
// =====================================================================
__global__ __launch_bounds__(256) void k3_out(
    const unsigned short* __restrict__ ows, const float* __restrict__ w_out,
    const float* __restrict__ b_out, const float* __restrict__ z,
    float* __restrict__ out)
{
    __shared__ unsigned int wlds[128 * 68];
    __shared__ unsigned int ob[128 * 68];
    const int tid = threadIdx.x;
    const int mbase = blockIdx.x * 128;
    const int lane = tid & 63;
    const int wid = tid >> 6;
    const int qn = lane & 15, gd = lane >> 4;

    const float4* wp4 = (const float4*)w_out;
    #pragma unroll 1
    for (int idx = tid; idx < 128 * 32; idx += 256) {
        const int row = idx >> 5, c4 = idx & 31;
        const float4 w4 = wp4[idx];
        wlds[row * 68 + 2 * c4]     = pack2(w4.x, w4.y);
        wlds[row * 68 + 2 * c4 + 1] = pack2(w4.z, w4.w);
    }
    const uint4* op4 = (const uint4*)ows;
    #pragma unroll 1
    for (int idx = tid; idx < 128 * 16; idx += 256) {
        const int row = idx >> 4, c = idx & 15;
        *(uint4*)&ob[row * 68 + 4 * c] = op4[(size_t)(mbase + row) * 16 + c];
    }
    __syncthreads();

    const f32x4 zero4 = {0.f, 0.f, 0.f, 0.f};
    f32x4 acc[2][8];
    #pragma unroll
    for (int rg = 0; rg < 2; ++rg)
        #pragma unroll
        for (int nt = 0; nt < 8; ++nt) acc[rg][nt] = zero4;

    #pragma unroll
    for (int kt = 0; kt < 4; ++kt) {
        FragU af[2];
        #pragma unroll
        for (int rg = 0; rg < 2; ++rg)
            af[rg].v = *(const bf16x8*)&ob[(wid * 32 + rg * 16 + qn) * 68 + 16 * kt + 4 * gd];
        #pragma unroll
        for (int nt = 0; nt < 8; ++nt) {
            FragU bf;
            bf.v = *(const bf16x8*)&wlds[(nt * 16 + qn) * 68 + 16 * kt + 4 * gd];
            #pragma unroll
            for (int rg = 0; rg < 2; ++rg)
                acc[rg][nt] = __builtin_amdgcn_mfma_f32_16x16x32_bf16(af[rg].v, bf.v, acc[rg][nt], 0, 0, 0);
        }
    }

    float bb[8];
    #pragma unroll
    for (int nt = 0; nt < 8; ++nt) bb[nt] = b_out[nt * 16 + qn];

    #pragma unroll
    for (int rg = 0; rg < 2; ++rg) {
        #pragma unroll
        for (int r = 0; r < 4; ++r) {
            const int grow = mbase + wid * 32 + rg * 16 + 4 * gd + r;
            const float* zr = z + (size_t)grow * DDIM;
            float* outr = out + (size_t)grow * DDIM;
            #pragma unroll
            for (int nt = 0; nt < 8; ++nt) {
                const int cg = nt * 16 + qn;
                outr[cg] = acc[rg][nt][r] + bb[nt] + zr[cg];
            }
        }
    }
}

extern "C" void kernel_launch(void* const* d_in, const int* in_sizes, int n_in,
                              void* d_out, int out_size, void* d_ws, size_t ws_size,
                              hipStream_t stream) {
    const float* z     = (const float*)d_in[0];
    const int*   mask  = (const int*)d_in[1];
    const float* ln_g  = (const float*)d_in[2];
    const float* ln_b  = (const float*)d_in[3];
    const float* w_qkv = (const float*)d_in[4];
    const float* b_qkv = (const float*)d_in[5];
    const float* w_out = (const float*)d_in[6];
    const float* b_out = (const float*)d_in[7];
    float* out = (float*)d_out;

    unsigned short* ws = (unsigned short*)d_ws;
    const size_t qE = (size_t)NSEQ * NH * LQ * DHD;  // 13,107,200
    unsigned short* qws = ws;
    unsigned short* kws = qws + qE;
    unsigned short* vws = kws + qE;
    unsigned short* shared_rgn = vws + qE;           // NROWS*DDIM bf16
    unsigned int*   znws = (unsigned int*)shared_rgn;
    unsigned short* ows  = shared_rgn;

    hipLaunchKernelGGL(k0_ln, dim3(NROWS / 64), dim3(256), 0, stream,
                       z, ln_g, ln_b, znws);
    hipLaunchKernelGGL(k1_qkv, dim3(2400), dim3(256), 0, stream,
                       znws, w_qkv, b_qkv, qws, kws, vws);
    hipLaunchKernelGGL(k2_attn_mfma, dim3(NSEQ * NH), dim3(256), 0, stream,
                       qws, kws, vws, mask, ows);
    hipLaunchKernelGGL(k3_out, dim3(800), dim3(256), 0, stream,
                       ows, w_out, b_out, z, out);
}

// Round 6
// 274.007 us; speedup vs baseline: 4.5530x; 1.0110x over previous
//
#include <hip/hip_runtime.h>

// Problem constants: B=1, L=320, D=128, H=4, DH=32
#define LQ 320
#define NSEQ 320
#define NROWS (NSEQ*LQ)   // 102400
#define DDIM 128
#define NH 4
#define DHD 32
#define LN_EPS 1e-5f
// 1/sqrt(32) * log2(e): folded into q so QK^T scores are in log2 domain
#define QSC2 0.25508652025545527f

typedef __bf16 bf16x8 __attribute__((ext_vector_type(8)));
typedef float f32x4 __attribute__((ext_vector_type(4)));
union FragU { unsigned int u[4]; bf16x8 v; };

__device__ inline unsigned short f2bf(float f) {
    unsigned int u = __float_as_uint(f);
    u += 0x7fffu + ((u >> 16) & 1u);
    return (unsigned short)(u >> 16);
}
__device__ inline unsigned int pack2(float a, float b) {
    return (unsigned int)f2bf(a) | ((unsigned int)f2bf(b) << 16);
}

// =====================================================================
// K0: LayerNorm -> zn bf16 [row][128] in ws. Grid 1600, block 256.
// =====================================================================
__global__ __launch_bounds__(256) void k0_ln(
    const float* __restrict__ z, const float* __restrict__ ln_g, const float* __restrict__ ln_b,
    unsigned int* __restrict__ znws)
{
    const int tid = threadIdx.x;
    const int rowbase = blockIdx.x * 64;
    const int lane = tid & 63;
    const int wid = tid >> 6;
    const float g0 = ln_g[2 * lane], g1 = ln_g[2 * lane + 1];
    const float bb0 = ln_b[2 * lane], bb1 = ln_b[2 * lane + 1];
    #pragma unroll 1
    for (int r = wid; r < 64; r += 4) {
        const int row = rowbase + r;
        const float2 v = *(const float2*)(z + (size_t)row * DDIM + 2 * lane);
        float s = v.x + v.y;
        float s2 = v.x * v.x + v.y * v.y;
        #pragma unroll
        for (int off = 32; off > 0; off >>= 1) {
            s  += __shfl_xor(s, off, 64);
            s2 += __shfl_xor(s2, off, 64);
        }
        const float mu = s * (1.0f / 128.0f);
        const float var = s2 * (1.0f / 128.0f) - mu * mu;
        const float rs = rsqrtf(var + LN_EPS);
        znws[(size_t)row * 64 + lane] =
            pack2((v.x - mu) * rs * g0 + bb0, (v.y - mu) * rs * g1 + bb1);
    }
}

// =====================================================================
// K1: QKV GEMM, 3-way N-split. Grid 2400 (sect = bx%3, m = bx/3), block 256.
// Round-6: zn A-frags read DIRECTLY from global (frag-aligned bf16,
// L2-resident) -> LDS = W chunk only, 34.8 KB -> 4 blocks/CU.
// Epilogue: C -> tr (reuses dead W LDS; row-major for q/k, col-major for v)
// -> wave-per-head ushort4 coalesced stores.
// q prescaled by 1/sqrt(DH)*log2e (K2 does exp2); v stored transposed.
// =====================================================================
__global__ __launch_bounds__(256) void k1_qkv(
    const unsigned short* __restrict__ znws, const float* __restrict__ w_qkv,
    const float* __restrict__ b_qkv,
    unsigned short* __restrict__ qws, unsigned short* __restrict__ kws,
    unsigned short* __restrict__ vws)
{
    __shared__ unsigned int wlds[128 * 68];   // 34816 B; later reused as tr
    const int tid = threadIdx.x;
    const int bx = blockIdx.x;
    const int sect = bx % 3;          // 0=q 1=k 2=v
    const int mbase = (bx / 3) * 128;
    const int lane = tid & 63;
    const int wid = tid >> 6;
    const int qn = lane & 15, gd = lane >> 4;

    // stage W chunk (fp32 -> bf16): rows sect*128..+127
    const float4* wp4 = (const float4*)w_qkv;
    #pragma unroll 1
    for (int idx = tid; idx < 128 * 32; idx += 256) {
        const int row = idx >> 5, c4 = idx & 31;
        const float4 w4 = wp4[(size_t)(sect * 128 + row) * 32 + c4];
        wlds[row * 68 + 2 * c4]     = pack2(w4.x, w4.y);
        wlds[row * 68 + 2 * c4 + 1] = pack2(w4.z, w4.w);
    }
    __syncthreads();

    const f32x4 zero4 = {0.f, 0.f, 0.f, 0.f};
    f32x4 acc[2][8];
    #pragma unroll
    for (int rg = 0; rg < 2; ++rg)
        #pragma unroll
        for (int nt = 0; nt < 8; ++nt) acc[rg][nt] = zero4;

    #pragma unroll
    for (int kt = 0; kt < 4; ++kt) {
        FragU af[2];
        #pragma unroll
        for (int rg = 0; rg < 2; ++rg)
            af[rg].v = *(const bf16x8*)&znws[
                (size_t)(mbase + wid * 32 + rg * 16 + qn) * DDIM + kt * 32 + gd * 8];
        #pragma unroll
        for (int nt = 0; nt < 8; ++nt) {
            FragU bf;
            bf.v = *(const bf16x8*)&wlds[(nt * 16 + qn) * 68 + 16 * kt + 4 * gd];
            #pragma unroll
            for (int rg = 0; rg < 2; ++rg)
                acc[rg][nt] = __builtin_amdgcn_mfma_f32_16x16x32_bf16(af[rg].v, bf.v, acc[rg][nt], 0, 0, 0);
        }
    }

    float bq[8];
    #pragma unroll
    for (int nt = 0; nt < 8; ++nt) bq[nt] = b_qkv[sect * 128 + nt * 16 + qn];
    const float sc = (sect == 0) ? QSC2 : 1.0f;

    __syncthreads();   // all waves done reading wlds
    unsigned short* tr = (unsigned short*)wlds;  // [128][132] (q/k: [row][col], v: [col][row])

    #pragma unroll
    for (int rg = 0; rg < 2; ++rg) {
        #pragma unroll
        for (int r = 0; r < 4; ++r) {
            const int row = wid * 32 + rg * 16 + 4 * gd + r;
            #pragma unroll
            for (int nt = 0; nt < 8; ++nt) {
                const int col = nt * 16 + qn;
                const unsigned short val = f2bf((acc[rg][nt][r] + bq[nt]) * sc);
                if (sect < 2) tr[row * 132 + col] = val;
                else          tr[col * 132 + row] = val;
            }
        }
    }
    __syncthreads();

    // wave-per-head coalesced stores (head h = wid)
    if (sect < 2) {
        unsigned short* dst = (sect == 0) ? qws : kws;
        #pragma unroll 1
        for (int k16 = 0; k16 < 16; ++k16) {
            const int off = lane * 4 + k16 * 1024;   // 0..16383 over [128 i][32 d]... per-wave: 4096
            // per wave: region [i_loc 0..127][d 0..31]; off covers lane*4 + k16*256
            const int o2 = lane * 4 + k16 * 256;
            const int i_loc = o2 >> 5, d = o2 & 31;
            const int grow = mbase + i_loc;
            const int n = grow / LQ;
            const int i = grow - n * LQ;
            const ushort4 val = *(const ushort4*)&tr[i_loc * 132 + wid * 32 + d];
            *(ushort4*)&dst[(((size_t)(n * NH + wid) * LQ + i)) * DHD + d] = val;
            (void)off;
        }
    } else {
        #pragma unroll 1
        for (int k16 = 0; k16 < 16; ++k16) {
            const int o2 = lane * 4 + k16 * 256;     // over [32 d][128 i]
            const int d = o2 >> 7, i_loc = o2 & 127;
            const int grow = mbase + i_loc;
            const int n = grow / LQ;
            const int i = grow - n * LQ;
            const ushort4 val = *(const ushort4*)&tr[(wid * 32 + d) * 132 + i_loc];
            *(ushort4*)&vws[((size_t)(n * NH + wid) * DHD + d) * LQ + i] = val;
        }
    }
}

// =====================================================================
// K2: MFMA attention, round-6. Grid 6400: block = (n,h, query-fifth);
// 256 thr (4 waves), ONE 16-query tile per wave (it-loop removed -> 5x
// more blocks, 6 resident/CU by LDS, latency hidden by TLP not ILP).
// Online softmax over two 160-key halves; bias folded into MFMA C;
// log2-domain scores (exp2 only); unnormalized-P PV, one 1/l at end.
// LDS: kT [320][20] 25.6KB + bias 1.25KB. V frags direct from global (L2).
// =====================================================================
#define KSTR 20
__global__ __launch_bounds__(256, 4) void k2_attn_mfma(
    const unsigned short* __restrict__ qws, const unsigned short* __restrict__ kws,
    const unsigned short* __restrict__ vtws, const int* __restrict__ mask,
    unsigned short* __restrict__ ows)
{
    __shared__ unsigned int kT[LQ * KSTR];        // 25.6 KB
    __shared__ __align__(16) float bias[LQ];      // 1.25 KB
    const int tid = threadIdx.x;
    const int bx = blockIdx.x;
    const int nh = bx / 5;
    const int qs = bx - nh * 5;
    const int lane = tid & 63;
    const int wid = tid >> 6;
    const int qn = lane & 15;
    const int gd = lane >> 4;

    const uint4* kp4 = (const uint4*)(kws + (size_t)nh * LQ * DHD);
    #pragma unroll 1
    for (int idx = tid; idx < LQ * 4; idx += 256) {
        const int r = idx >> 2, c4 = idx & 3;
        *(uint4*)&kT[r * KSTR + 4 * c4] = kp4[idx];
    }
    for (int i = tid; i < LQ; i += 256) bias[i] = (mask[i] > 0) ? 0.f : -1e30f;
    __syncthreads();

    const f32x4 zero4 = {0.f, 0.f, 0.f, 0.f};
    const int alo = (((gd & 1) << 5) | qn) << 2;
    const int ahi = alo + 64;
    const bool hiT = (gd >= 2);
    const int n = nh >> 2, h = nh & 3;
    const unsigned short* vbase = vtws + (size_t)nh * DHD * LQ;  // [32][320] bf16

    const int qt = qs * 4 + wid;

    FragU qf;
    qf.v = *(const bf16x8*)(qws + ((size_t)nh * LQ + qt * 16 + qn) * DHD + 8 * gd);

    f32x4 o0 = zero4, o1 = zero4;
    float m_run = -1e30f;
    float l_run = 0.f;

    #pragma unroll 1
    for (int half = 0; half < 2; ++half) {
        const int tb = half * 10;

        f32x4 st[10];
        #pragma unroll
        for (int kt = 0; kt < 10; ++kt) {
            const int ktg = tb + kt;
            FragU kf;
            const uint4 kv = *(const uint4*)&kT[(ktg * 16 + qn) * KSTR + 4 * gd];
            kf.u[0] = kv.x; kf.u[1] = kv.y; kf.u[2] = kv.z; kf.u[3] = kv.w;
            const f32x4 c0 = *(const f32x4*)&bias[ktg * 16 + 4 * gd];
            st[kt] = __builtin_amdgcn_mfma_f32_16x16x32_bf16(kf.v, qf.v, c0, 0, 0, 0);
        }

        float mh = -1e30f;
        #pragma unroll
        for (int kt = 0; kt < 10; ++kt)
            mh = fmaxf(mh, fmaxf(fmaxf(st[kt][0], st[kt][1]), fmaxf(st[kt][2], st[kt][3])));
        mh = fmaxf(mh, __shfl_xor(mh, 16, 64));
        mh = fmaxf(mh, __shfl_xor(mh, 32, 64));
        const float m_new = fmaxf(m_run, mh);
        const float scl = __builtin_amdgcn_exp2f(m_run - m_new);
        m_run = m_new;
        l_run *= scl;
        o0 *= scl;
        o1 *= scl;

        #pragma unroll
        for (int kt = 0; kt < 10; ++kt) {
            st[kt][0] = __builtin_amdgcn_exp2f(st[kt][0] - m_new);
            st[kt][1] = __builtin_amdgcn_exp2f(st[kt][1] - m_new);
            st[kt][2] = __builtin_amdgcn_exp2f(st[kt][2] - m_new);
            st[kt][3] = __builtin_amdgcn_exp2f(st[kt][3] - m_new);
            l_run += st[kt][0] + st[kt][1] + st[kt][2] + st[kt][3];
        }

        #pragma unroll
        for (int kc = 0; kc < 5; ++kc) {
            const int t0 = 2 * kc, t1 = 2 * kc + 1;
            const unsigned int p01a = pack2(st[t0][0], st[t0][1]);
            const unsigned int p23a = pack2(st[t0][2], st[t0][3]);
            const unsigned int p01b = pack2(st[t1][0], st[t1][1]);
            const unsigned int p23b = pack2(st[t1][2], st[t1][3]);
            FragU pa;
            {
                const int a0 = __builtin_amdgcn_ds_bpermute(alo, (int)p01a);
                const int b0 = __builtin_amdgcn_ds_bpermute(alo, (int)p01b);
                const int a1 = __builtin_amdgcn_ds_bpermute(alo, (int)p23a);
                const int b1 = __builtin_amdgcn_ds_bpermute(alo, (int)p23b);
                const int a2 = __builtin_amdgcn_ds_bpermute(ahi, (int)p01a);
                const int b2 = __builtin_amdgcn_ds_bpermute(ahi, (int)p01b);
                const int a3 = __builtin_amdgcn_ds_bpermute(ahi, (int)p23a);
                const int b3 = __builtin_amdgcn_ds_bpermute(ahi, (int)p23b);
                pa.u[0] = (unsigned int)(hiT ? b0 : a0);
                pa.u[1] = (unsigned int)(hiT ? b1 : a1);
                pa.u[2] = (unsigned int)(hiT ? b2 : a2);
                pa.u[3] = (unsigned int)(hiT ? b3 : a3);
            }
            FragU bv0, bv1;
            const int koff = half * 160 + 32 * kc + 8 * gd;
            bv0.v = *(const bf16x8*)(vbase + (0 * 16 + qn) * LQ + koff);
            bv1.v = *(const bf16x8*)(vbase + (1 * 16 + qn) * LQ + koff);
            o0 = __builtin_amdgcn_mfma_f32_16x16x32_bf16(pa.v, bv0.v, o0, 0, 0, 0);
            o1 = __builtin_amdgcn_mfma_f32_16x16x32_bf16(pa.v, bv1.v, o1, 0, 0, 0);
        }
    }

    l_run += __shfl_xor(l_run, 16, 64);
    l_run += __shfl_xor(l_run, 32, 64);
    const float inv = 1.0f / l_run;

    #pragma unroll
    for (int r = 0; r < 4; ++r) {
        const int qg = qt * 16 + 4 * gd + r;
        unsigned short* orow = ows + ((size_t)(n * LQ + qg)) * DDIM + h * DHD + qn;
        orow[0]  = f2bf(o0[r] * inv);
        orow[16] = f2bf(o1[r] * inv);
    }
}

// =====================================================================
// K3: out projection + residual, MFMA. Grid 800, block 256.
// Round-6: o A-frags direct from global -> LDS = w_out only (34.8 KB)
// -> 4 blocks/CU.
// =====================================================================
__global__ __launch_bounds__(256) void k3_out(
    const unsigned short* __restrict__ ows, const float* __restrict__ w_out,
    const float* __restrict__ b_out, const float* __restrict__ z,
    float* __restrict__ out)
{
    __shared__ unsigned int wlds[128 * 68];
    const int tid = threadIdx.x;
    const int mbase = blockIdx.x * 128;
    const int lane = tid & 63;
    const int wid = tid >> 6;
    const int qn = lane & 15, gd = lane >> 4;

    const float4* wp4 = (const float4*)w_out;
    #pragma unroll 1
    for (int idx = tid; idx < 128 * 32; idx += 256) {
        const int row = idx >> 5, c4 = idx & 31;
        const float4 w4 = wp4[idx];
        wlds[row * 68 + 2 * c4]     = pack2(w4.x, w4.y);
        wlds[row * 68 + 2 * c4 + 1] = pack2(w4.z, w4.w);
    }
    __syncthreads();

    const f32x4 zero4 = {0.f, 0.f, 0.f, 0.f};
    f32x4 acc[2][8];
    #pragma unroll
    for (int rg = 0; rg < 2; ++rg)
        #pragma unroll
        for (int nt = 0; nt < 8; ++nt) acc[rg][nt] = zero4;

    #pragma unroll
    for (int kt = 0; kt < 4; ++kt) {
        FragU af[2];
        #pragma unroll
        for (int rg = 0; rg < 2; ++rg)
            af[rg].v = *(const bf16x8*)&ows[
                (size_t)(mbase + wid * 32 + rg * 16 + qn) * DDIM + kt * 32 + gd * 8];
        #pragma unroll
        for (int nt = 0; nt < 8; ++nt) {
            FragU bf;
            bf.v = *(const bf16x8*)&wlds[(nt * 16 + qn) * 68 + 16 * kt + 4 * gd];
            #pragma unroll
            for (int rg = 0; rg < 2; ++rg)
                acc[rg][nt] = __builtin_amdgcn_mfma_f32_16x16x32_bf16(af[rg].v, bf.v, acc[rg][nt], 0, 0, 0);
        }
    }

    float bb[8];
    #pragma unroll
    for (int nt = 0; nt < 8; ++nt) bb[nt] = b_out[nt * 16 + qn];

    #pragma unroll
    for (int rg = 0; rg < 2; ++rg) {
        #pragma unroll
        for (int r = 0; r < 4; ++r) {
            const int grow = mbase + wid * 32 + rg * 16 + 4 * gd + r;
            const float* zr = z + (size_t)grow * DDIM;
            float* outr = out + (size_t)grow * DDIM;
            #pragma unroll
            for (int nt = 0; nt < 8; ++nt) {
                const int cg = nt * 16 + qn;
                outr[cg] = acc[rg][nt][r] + bb[nt] + zr[cg];
            }
        }
    }
}

extern "C" void kernel_launch(void* const* d_in, const int* in_sizes, int n_in,
                              void* d_out, int out_size, void* d_ws, size_t ws_size,
                              hipStream_t stream) {
    const float* z     = (const float*)d_in[0];
    const int*   mask  = (const int*)d_in[1];
    const float* ln_g  = (const float*)d_in[2];
    const float* ln_b  = (const float*)d_in[3];
    const float* w_qkv = (const float*)d_in[4];
    const float* b_qkv = (const float*)d_in[5];
    const float* w_out = (const float*)d_in[6];
    const float* b_out = (const float*)d_in[7];
    float* out = (float*)d_out;

    unsigned short* ws = (unsigned short*)d_ws;
    const size_t qE = (size_t)NSEQ * NH * LQ * DHD;  // 13,107,200
    unsigned short* qws = ws;
    unsigned short* kws = qws + qE;
    unsigned short* vws = kws + qE;
    unsigned short* shared_rgn = vws + qE;           // NROWS*DDIM bf16
    unsigned int*   znws = (unsigned int*)shared_rgn;
    unsigned short* ows  = shared_rgn;

    hipLaunchKernelGGL(k0_ln, dim3(NROWS / 64), dim3(256), 0, stream,
                       z, ln_g, ln_b, znws);
    hipLaunchKernelGGL(k1_qkv, dim3(2400), dim3(256), 0, stream,
                       (const unsigned short*)znws, w_qkv, b_qkv, qws, kws, vws);
    hipLaunchKernelGGL(k2_attn_mfma, dim3(6400), dim3(256), 0, stream,
                       qws, kws, vws, mask, ows);
    hipLaunchKernelGGL(k3_out, dim3(800), dim3(256), 0, stream,
                       ows, w_out, b_out, z, out);
}